// Round 9
// baseline (21075.992 us; speedup 1.0000x reference)
//
#include <hip/hip_runtime.h>
#include <cstddef>

// SchNet fwd energy + force bwd, MI355X. Round 9: tiled edge kernels with
// bf16 W1/W2 staged in LDS (kills the L2-latency-bound W2 re-streaming that
// made R8 edge kernels 19% VALUBusy). f32 in/out, fp32 accumulate.

#define FD     128
#define NRBF   20
#define CUTF   5.0f
#define PI_F   3.14159265358979f

typedef unsigned short u16;
typedef unsigned int   u32;

__device__ __forceinline__ float u16f(u16 x){ union{u32 i; float f;} v; v.i=((u32)x)<<16; return v.f; }
__device__ __forceinline__ float blo(u32 u){ union{u32 i; float f;} v; v.i=u<<16; return v.f; }
__device__ __forceinline__ float bhi(u32 u){ union{u32 i; float f;} v; v.i=u&0xffff0000u; return v.f; }
__device__ __forceinline__ u16 f16r(float f){ union{float f; u32 i;} v; v.f=f; u32 r=v.i+0x7fffu+((v.i>>16)&1u); return (u16)(r>>16); }
__device__ __forceinline__ float sspf(float x){ return fmaxf(x,0.f)+log1pf(expf(-fabsf(x)))-0.6931471805599453f; }
__device__ __forceinline__ float sigf(float x){ return 1.f/(1.f+expf(-x)); }
__device__ __forceinline__ float fcutf(float d){ return (d < CUTF) ? 0.5f*(cosf(PI_F*d/CUTF)+1.f) : 0.f; }

__global__ __launch_bounds__(256) void k_zero(float* __restrict__ p, int n){
  int i = blockIdx.x*256 + threadIdx.x;
  if(i < n) p[i] = 0.f;
}

__global__ __launch_bounds__(256) void k_embed(const float* __restrict__ emb, const int* __restrict__ Z,
                                               float* __restrict__ X0, int n){
  int idx = blockIdx.x*256 + threadIdx.x;
  if(idx >= n) return;
  int a = idx >> 7, f = idx & 127;
  X0[idx] = emb[Z[a]*FD + f];
}

__global__ __launch_bounds__(256) void k_edge_geom(const float* __restrict__ pos,
    const int* __restrict__ Ii, const int* __restrict__ Ij,
    float* __restrict__ De, float* __restrict__ DBe, int E){
  int e = blockIdx.x*256 + threadIdx.x;
  if(e >= E) return;
  int i = Ii[e], j = Ij[e];
  float dx = pos[j*3+0]-pos[i*3+0];
  float dy = pos[j*3+1]-pos[i*3+1];
  float dz = pos[j*3+2]-pos[i*3+2];
  De[e] = sqrtf(dx*dx+dy*dy+dz*dz + 1e-12f);
  DBe[e] = 0.f;
}

// out = act(A@B(^T) + bias + res) * mul ; rows guarded by Nr. (unchanged, verified)
__global__ __launch_bounds__(256) void k_gemm32(const float* __restrict__ A, const float* __restrict__ B,
    const float* __restrict__ bias, const float* __restrict__ res,
    const float* __restrict__ mul, float* __restrict__ out1, float* __restrict__ out2,
    int transB, int act, int Nr){
  __shared__ float As[64*132];
  const int tid = threadIdx.x;
  const int rb = blockIdx.x * 64;
  for(int q=0;q<8;q++){
    int e = q*256 + tid;
    int r = e >> 5, c = (e & 31) * 4;
    int rr = rb + r; if(rr >= Nr) rr = Nr-1;
    *(float4*)&As[r*132 + c] = *(const float4*)(A + (size_t)rr*FD + c);
  }
  __syncthreads();
  const int r0 = (tid >> 4) * 4;
  const int f0 = (tid & 15) * 8;
  float acc[4][8] = {};
  if(!transB){
    for(int k=0;k<128;k++){
      float a[4] = {As[(r0+0)*132+k], As[(r0+1)*132+k], As[(r0+2)*132+k], As[(r0+3)*132+k]};
      float4 b0 = *(const float4*)(B + k*FD + f0);
      float4 b1 = *(const float4*)(B + k*FD + f0 + 4);
      float b[8] = {b0.x,b0.y,b0.z,b0.w,b1.x,b1.y,b1.z,b1.w};
      #pragma unroll
      for(int i=0;i<4;i++)
        #pragma unroll
        for(int j=0;j<8;j++) acc[i][j] += a[i]*b[j];
    }
  } else {
    for(int k=0;k<128;k++){
      float a[4] = {As[(r0+0)*132+k], As[(r0+1)*132+k], As[(r0+2)*132+k], As[(r0+3)*132+k]};
      float b[8];
      #pragma unroll
      for(int j=0;j<8;j++) b[j] = B[(size_t)(f0+j)*FD + k];
      #pragma unroll
      for(int i=0;i<4;i++)
        #pragma unroll
        for(int j=0;j<8;j++) acc[i][j] += a[i]*b[j];
    }
  }
  float bv[8];
  #pragma unroll
  for(int j=0;j<8;j++) bv[j] = bias ? bias[f0+j] : 0.f;
  #pragma unroll
  for(int rr=0;rr<4;rr++){
    int row = rb + r0 + rr;
    if(row >= Nr) break;
    size_t base = (size_t)row*FD + f0;
    float y[8];
    #pragma unroll
    for(int j=0;j<8;j++) y[j] = acc[rr][j] + bv[j];
    if(res){
      float4 r1 = *(const float4*)(res+base);
      float4 r2 = *(const float4*)(res+base+4);
      y[0]+=r1.x; y[1]+=r1.y; y[2]+=r1.z; y[3]+=r1.w;
      y[4]+=r2.x; y[5]+=r2.y; y[6]+=r2.z; y[7]+=r2.w;
    }
    if(mul){
      float4 m1 = *(const float4*)(mul+base);
      float4 m2 = *(const float4*)(mul+base+4);
      y[0]*=m1.x; y[1]*=m1.y; y[2]*=m1.z; y[3]*=m1.w;
      y[4]*=m2.x; y[5]*=m2.y; y[6]*=m2.z; y[7]*=m2.w;
    }
    if(act){
      *(float4*)(out1+base)   = make_float4(sspf(y[0]),sspf(y[1]),sspf(y[2]),sspf(y[3]));
      *(float4*)(out1+base+4) = make_float4(sspf(y[4]),sspf(y[5]),sspf(y[6]),sspf(y[7]));
      *(float4*)(out2+base)   = make_float4(sigf(y[0]),sigf(y[1]),sigf(y[2]),sigf(y[3]));
      *(float4*)(out2+base+4) = make_float4(sigf(y[4]),sigf(y[5]),sigf(y[6]),sigf(y[7]));
    } else {
      *(float4*)(out1+base)   = make_float4(y[0],y[1],y[2],y[3]);
      *(float4*)(out1+base+4) = make_float4(y[4],y[5],y[6],y[7]);
    }
  }
}

// ---- Tiled edge forward: 32 edges/block, 8 threads/edge (16 f each). ----
// W1/W2 staged once per block in LDS (bf16).
__global__ __launch_bounds__(256) void k_edge_fwd_t(
    const float* __restrict__ h,
    const int* __restrict__ Ii, const int* __restrict__ Ij,
    const float* __restrict__ De,
    const float* __restrict__ W1, const float* __restrict__ b1,
    const float* __restrict__ W2, const float* __restrict__ b2,
    float* __restrict__ agg, int E){
  __shared__ u16 sW2[128*136];   // [c][f] pitch 136, bf16 (34.8 KB)
  __shared__ u16 sW1[NRBF*128];  // 5 KB
  __shared__ u16 sP [32*136];    // P[t][c] bf16 (8.7 KB)
  const int tid = threadIdx.x;
  for(int q=0;q<16;q++){
    int idx = q*256 + tid;               // 4096 float4 = 16384 elems
    int c = idx >> 5, f4 = (idx & 31)*4;
    float4 v = *(const float4*)(W2 + c*FD + f4);
    sW2[c*136+f4+0]=f16r(v.x); sW2[c*136+f4+1]=f16r(v.y);
    sW2[c*136+f4+2]=f16r(v.z); sW2[c*136+f4+3]=f16r(v.w);
  }
  for(int q=0;q<10;q++){ int idx=q*256+tid; sW1[idx]=f16r(W1[idx]); }
  __syncthreads();
  const int t = tid >> 3, oq = tid & 7;
  const int e = blockIdx.x*32 + t;
  const bool ok = (e < E);
  const float step = CUTF/19.0f;
  const float coef = -0.5f/(step*step);
  int i=0, j=0; float fc=0.f;
  if(ok){
    i = Ii[e]; j = Ij[e];
    float d = De[e]; fc = fcutf(d);
    float rb[NRBF];
    #pragma unroll
    for(int k=0;k<NRBF;k++){ float x = d - step*(float)k; rb[k] = expf(coef*x*x); }
    for(int cc=0; cc<16; cc++){
      int c = oq*16 + cc;
      float tv = b1[c];
      #pragma unroll
      for(int k=0;k<NRBF;k++) tv += rb[k]*u16f(sW1[k*128 + c]);
      sP[t*136 + c] = f16r(sspf(tv));
    }
  }
  __syncthreads();
  if(ok){
    const int f0 = oq*16;
    float wf[16];
    #pragma unroll
    for(int q=0;q<16;q++) wf[q] = b2[f0+q];
    for(int c=0;c<128;c++){
      float p = u16f(sP[t*136 + c]);
      uint4 w0 = *(const uint4*)&sW2[c*136 + f0];
      uint4 w1 = *(const uint4*)&sW2[c*136 + f0 + 8];
      wf[0]+=p*blo(w0.x); wf[1]+=p*bhi(w0.x); wf[2]+=p*blo(w0.y); wf[3]+=p*bhi(w0.y);
      wf[4]+=p*blo(w0.z); wf[5]+=p*bhi(w0.z); wf[6]+=p*blo(w0.w); wf[7]+=p*bhi(w0.w);
      wf[8]+=p*blo(w1.x); wf[9]+=p*bhi(w1.x); wf[10]+=p*blo(w1.y); wf[11]+=p*bhi(w1.y);
      wf[12]+=p*blo(w1.z); wf[13]+=p*bhi(w1.z); wf[14]+=p*blo(w1.w); wf[15]+=p*bhi(w1.w);
    }
    const size_t hrow = (size_t)j*FD + f0;
    const size_t arow = (size_t)i*FD + f0;
    #pragma unroll
    for(int q4=0;q4<4;q4++){
      float4 hv = *(const float4*)(h + hrow + q4*4);
      atomicAdd(&agg[arow + q4*4+0], hv.x*wf[q4*4+0]*fc);
      atomicAdd(&agg[arow + q4*4+1], hv.y*wf[q4*4+1]*fc);
      atomicAdd(&agg[arow + q4*4+2], hv.z*wf[q4*4+2]*fc);
      atomicAdd(&agg[arow + q4*4+3], hv.w*wf[q4*4+3]*fc);
    }
  }
}

// ---- Tiled edge backward: 16 edges/block, 16 threads/edge (8 f each). ----
__global__ __launch_bounds__(256) void k_edge_bwd_t(
    const float* __restrict__ h, const float* __restrict__ AB,
    const int* __restrict__ Ii, const int* __restrict__ Ij,
    const float* __restrict__ De,
    const float* __restrict__ W1, const float* __restrict__ b1,
    const float* __restrict__ W2, const float* __restrict__ b2,
    float* __restrict__ DBe, float* __restrict__ HB, int E){
  __shared__ u16 sW2[128*136];   // [c][f] bf16
  __shared__ u16 sW1[NRBF*128];
  __shared__ u16 sPb[16*136];    // P[t][c] -> Wbar[t][f]
  __shared__ u16 sSt[16*136];    // sigma(t)[t][c] -> tbar
  __shared__ u16 sWf[16*136];    // Wf[t][f]
  __shared__ float sfb[16];
  const int tid = threadIdx.x;
  for(int q=0;q<16;q++){
    int idx = q*256 + tid;
    int c = idx >> 5, f4 = (idx & 31)*4;
    float4 v = *(const float4*)(W2 + c*FD + f4);
    sW2[c*136+f4+0]=f16r(v.x); sW2[c*136+f4+1]=f16r(v.y);
    sW2[c*136+f4+2]=f16r(v.z); sW2[c*136+f4+3]=f16r(v.w);
  }
  for(int q=0;q<10;q++){ int idx=q*256+tid; sW1[idx]=f16r(W1[idx]); }
  __syncthreads();
  const int t = tid >> 4, oq = tid & 15;
  const int e = blockIdx.x*16 + t;
  const bool ok = (e < E);
  const float step = CUTF/19.0f;
  const float coef = -0.5f/(step*step);
  int i=0, j=0; float fc=0.f, d=0.f;
  if(ok){
    i = Ii[e]; j = Ij[e]; d = De[e]; fc = fcutf(d);
    float rb[NRBF];
    #pragma unroll
    for(int k=0;k<NRBF;k++){ float x = d - step*(float)k; rb[k] = expf(coef*x*x); }
    for(int cc=0; cc<8; cc++){
      int c = oq*8 + cc;
      float tv = b1[c];
      #pragma unroll
      for(int k=0;k<NRBF;k++) tv += rb[k]*u16f(sW1[k*128 + c]);
      sPb[t*136 + c] = f16r(sspf(tv));
      sSt[t*136 + c] = f16r(sigf(tv));
    }
  }
  __syncthreads();
  const int f0 = oq*8;
  if(ok){ // Wf[t][f0..f0+8] = b2 + P@W2
    float wf[8];
    #pragma unroll
    for(int q=0;q<8;q++) wf[q] = b2[f0+q];
    for(int c=0;c<128;c++){
      float p = u16f(sPb[t*136 + c]);
      uint4 w = *(const uint4*)&sW2[c*136 + f0];
      wf[0]+=p*blo(w.x); wf[1]+=p*bhi(w.x); wf[2]+=p*blo(w.y); wf[3]+=p*bhi(w.y);
      wf[4]+=p*blo(w.z); wf[5]+=p*bhi(w.z); wf[6]+=p*blo(w.w); wf[7]+=p*bhi(w.w);
    }
    #pragma unroll
    for(int q=0;q<8;q++) sWf[t*136 + f0 + q] = f16r(wf[q]);
  }
  __syncthreads();
  if(ok){ // hbar scatter, Wbar into sPb, fbar partial
    float4 a0 = *(const float4*)(AB + (size_t)i*FD + f0);
    float4 a1 = *(const float4*)(AB + (size_t)i*FD + f0 + 4);
    float4 h0 = *(const float4*)(h  + (size_t)j*FD + f0);
    float4 h1 = *(const float4*)(h  + (size_t)j*FD + f0 + 4);
    float av[8] = {a0.x,a0.y,a0.z,a0.w,a1.x,a1.y,a1.z,a1.w};
    float hv[8] = {h0.x,h0.y,h0.z,h0.w,h1.x,h1.y,h1.z,h1.w};
    float pf = 0.f;
    #pragma unroll
    for(int q=0;q<8;q++){
      float wfv = u16f(sWf[t*136 + f0 + q]);
      atomicAdd(&HB[(size_t)j*FD + f0 + q], av[q]*wfv*fc);
      float g = av[q]*hv[q];
      pf += g*wfv;
      sPb[t*136 + f0 + q] = f16r(g*fc);
    }
    pf += __shfl_xor(pf,1); pf += __shfl_xor(pf,2);
    pf += __shfl_xor(pf,4); pf += __shfl_xor(pf,8);
    if(oq == 0) sfb[t] = pf;
  }
  __syncthreads();
  if(ok){ // Pbar[t][c0..c0+8] = Wbar@W2^T ; tbar = Pbar*sigma in place
    const int c0 = oq*8;
    float pb[8] = {};
    for(int fch=0; fch<16; fch++){
      uint4 wbv = *(const uint4*)&sPb[t*136 + fch*8];
      float wb[8] = {blo(wbv.x),bhi(wbv.x),blo(wbv.y),bhi(wbv.y),blo(wbv.z),bhi(wbv.z),blo(wbv.w),bhi(wbv.w)};
      #pragma unroll
      for(int c8=0;c8<8;c8++){
        uint4 w = *(const uint4*)&sW2[(c0+c8)*136 + fch*8];
        pb[c8] += wb[0]*blo(w.x)+wb[1]*bhi(w.x)+wb[2]*blo(w.y)+wb[3]*bhi(w.y)
                + wb[4]*blo(w.z)+wb[5]*bhi(w.z)+wb[6]*blo(w.w)+wb[7]*bhi(w.w);
      }
    }
    #pragma unroll
    for(int c8=0;c8<8;c8++){
      int idx = t*136 + c0 + c8;
      sSt[idx] = f16r(pb[c8] * u16f(sSt[idx]));
    }
  }
  __syncthreads();
  if(ok){ // rbar = tbar@W1^T (partial over this thread's 8 c), reduce, dbar
    float a20[NRBF] = {};
    #pragma unroll
    for(int c8=0;c8<8;c8++){
      int c = oq*8 + c8;
      float tv = u16f(sSt[t*136 + c]);
      #pragma unroll
      for(int k=0;k<NRBF;k++) a20[k] += tv * u16f(sW1[k*128 + c]);
    }
    #pragma unroll
    for(int k=0;k<NRBF;k++){
      a20[k] += __shfl_xor(a20[k],1); a20[k] += __shfl_xor(a20[k],2);
      a20[k] += __shfl_xor(a20[k],4); a20[k] += __shfl_xor(a20[k],8);
    }
    if(oq == 0){
      float drb = 0.f;
      #pragma unroll
      for(int k=0;k<NRBF;k++){
        float x = d - step*(float)k;
        float rbv = expf(coef*x*x);
        drb += a20[k] * rbv * 2.f*coef*x;
      }
      float dfc = (d < CUTF) ? (-0.5f*(PI_F/CUTF)*sinf(PI_F*d/CUTF)) : 0.f;
      DBe[e] += drb + sfb[t]*dfc;
    }
  }
}

// fused atomwise head + head-backward (unchanged, verified)
__global__ __launch_bounds__(256) void k_head(const float* __restrict__ X3,
    const float* __restrict__ aW1, const float* __restrict__ ab1,
    const float* __restrict__ aW2, const float* __restrict__ ab2,
    const int* __restrict__ mol, float* __restrict__ Emol, float* __restrict__ XB, int N){
  __shared__ float sx[64*129];
  __shared__ float sg[64*65];
  const int tid = threadIdx.x;
  const int base = blockIdx.x*64;
  for(int q=0;q<8;q++){
    int ee = q*256 + tid;
    int r = ee >> 5, c = (ee & 31)*4;
    int row = base + r; if(row >= N) row = N-1;
    float4 v = *(const float4*)(X3 + (size_t)row*FD + c);
    sx[r*129 + c+0] = v.x; sx[r*129 + c+1] = v.y;
    sx[r*129 + c+2] = v.z; sx[r*129 + c+3] = v.w;
  }
  __syncthreads();
  {
    const int a = tid >> 2, q = tid & 3;
    float pe = 0.f;
    for(int cc=0; cc<16; cc++){
      int c = q*16 + cc;
      float u = ab1[c];
      for(int f=0; f<128; f++) u += sx[a*129 + f]*aW1[f*64 + c];
      pe += sspf(u)*aW2[c];
      sg[a*65 + c] = sigf(u)*aW2[c];
    }
    pe += __shfl_xor(pe, 1);
    pe += __shfl_xor(pe, 2);
    if(q == 0 && base + a < N) atomicAdd(&Emol[mol[base + a]], pe + ab2[0]);
  }
  __syncthreads();
  {
    const int f = tid & 127, g2 = tid >> 7;
    float acc[32];
    #pragma unroll
    for(int q=0;q<32;q++) acc[q]=0.f;
    for(int c=0;c<64;c++){
      float w = aW1[f*64 + c];
      #pragma unroll
      for(int q=0;q<32;q++) acc[q] += sg[(g2*32+q)*65 + c]*w;
    }
    #pragma unroll
    for(int q=0;q<32;q++){
      int row = base + g2*32 + q;
      if(row < N) XB[(size_t)row*FD + f] = acc[q];
    }
  }
}

__global__ __launch_bounds__(256) void k_grad(const float* __restrict__ pos,
    const int* __restrict__ Ii, const int* __restrict__ Ij,
    const float* __restrict__ De, const float* __restrict__ DBe,
    float* __restrict__ G, int E){
  int e = blockIdx.x*256 + threadIdx.x;
  if(e >= E) return;
  float s = DBe[e] / De[e];
  int i = Ii[e], j = Ij[e];
  float dx = s*(pos[i*3+0]-pos[j*3+0]);
  float dy = s*(pos[i*3+1]-pos[j*3+1]);
  float dz = s*(pos[i*3+2]-pos[j*3+2]);
  atomicAdd(&G[i*3+0], dx); atomicAdd(&G[i*3+1], dy); atomicAdd(&G[i*3+2], dz);
  atomicAdd(&G[j*3+0], -dx); atomicAdd(&G[j*3+1], -dy); atomicAdd(&G[j*3+2], -dz);
}

__global__ __launch_bounds__(256) void k_norm(const float* __restrict__ G,
    const int* __restrict__ mol, u32* __restrict__ maxnU, int N){
  int n = blockIdx.x*256 + threadIdx.x;
  if(n >= N) return;
  float ax = G[n*3], ay = G[n*3+1], az = G[n*3+2];
  float nrm = sqrtf(ax*ax+ay*ay+az*az);
  atomicMax(&maxnU[mol[n]], __float_as_uint(nrm));
}

__global__ __launch_bounds__(256) void k_apply(const float* __restrict__ G,
    const int* __restrict__ mol, const u32* __restrict__ maxnU,
    float* __restrict__ outA, int N){
  int n = blockIdx.x*256 + threadIdx.x;
  if(n >= N) return;
  float mx = __uint_as_float(maxnU[mol[n]]);
  float coefc = fminf(1.0f/fmaxf(mx, 1e-8f), 1.0f);
  outA[n*3+0] = -G[n*3+0]*coefc;
  outA[n*3+1] = -G[n*3+1]*coefc;
  outA[n*3+2] = -G[n*3+2]*coefc;
}

extern "C" void kernel_launch(void* const* d_in, const int* in_sizes, int n_in,
                              void* d_out, int out_size, void* d_ws, size_t ws_size,
                              hipStream_t stream) {
  (void)n_in;
  const float* pos  = (const float*)d_in[0];
  const float* emb  = (const float*)d_in[1];
  const float* in2f = (const float*)d_in[2];
  const float* fW1  = (const float*)d_in[3];
  const float* fb1  = (const float*)d_in[4];
  const float* fW2  = (const float*)d_in[5];
  const float* fb2  = (const float*)d_in[6];
  const float* oW1  = (const float*)d_in[7];
  const float* ob1  = (const float*)d_in[8];
  const float* oW2  = (const float*)d_in[9];
  const float* ob2  = (const float*)d_in[10];
  const float* aW1  = (const float*)d_in[11];
  const float* ab1  = (const float*)d_in[12];
  const float* aW2  = (const float*)d_in[13];
  const float* ab2  = (const float*)d_in[14];
  const int*   Z    = (const int*)d_in[15];
  const int*   Ii   = (const int*)d_in[16];
  const int*   Ij   = (const int*)d_in[17];
  const int*   mol  = (const int*)d_in[18];
  const int N = in_sizes[15];
  const int E = in_sizes[16];
  const int M = out_size - N*3;
  const size_t NFE = (size_t)N*FD;
  float* outF = (float*)d_out;
  float* outE = outF + (size_t)N*3;
  float* ws = (float*)d_ws;
  if(ws_size < (11*NFE + 2*(size_t)E)*4) return;

  float* X0  = ws;
  float* SV0 = ws + 4*NFE;
  float* H   = ws + 7*NFE;
  float* AGG = ws + 8*NFE;
  float* XB  = ws + 9*NFE;
  float* HB  = ws + 10*NFE;
  float* De  = ws + 11*NFE;
  float* DBe = De + E;
  float* G    = AGG;
  u32*  maxnU = (u32*)H;

  const int gN   = (int)((NFE + 255)/256);
  const int gE   = (E + 255)/256;
  const int gT32 = (E + 31)/32;
  const int gT16 = (E + 15)/16;
  const int gRow = (N + 63)/64;

  k_embed<<<gN,256,0,stream>>>(emb, Z, X0, (int)NFE);
  k_edge_geom<<<gE,256,0,stream>>>(pos, Ii, Ij, De, DBe, E);
  for(int l=0;l<3;l++){
    float* Xl  = X0 + (size_t)l*NFE;
    float* Xn  = X0 + (size_t)(l+1)*NFE;
    float* SVl = SV0 + (size_t)l*NFE;
    k_gemm32<<<gRow,256,0,stream>>>(Xl, in2f + l*16384, nullptr, nullptr, nullptr, H, nullptr, 0, 0, N);
    k_zero<<<gN,256,0,stream>>>(AGG, (int)NFE);
    k_edge_fwd_t<<<gT32,256,0,stream>>>(H, Ii, Ij, De, fW1 + l*2560, fb1 + l*128, fW2 + l*16384, fb2 + l*128, AGG, E);
    k_gemm32<<<gRow,256,0,stream>>>(AGG, oW1 + l*16384, ob1 + l*128, nullptr, nullptr, H, SVl, 0, 1, N);
    k_gemm32<<<gRow,256,0,stream>>>(H, oW2 + l*16384, ob2 + l*128, Xl, nullptr, Xn, nullptr, 0, 0, N);
  }
  k_zero<<<(M+255)/256,256,0,stream>>>(outE, M);
  k_head<<<gRow,256,0,stream>>>(X0 + 3*NFE, aW1, ab1, aW2, ab2, mol, outE, XB, N);
  for(int l=2;l>=0;l--){
    float* Xl  = X0 + (size_t)l*NFE;
    float* SVl = SV0 + (size_t)l*NFE;
    k_gemm32<<<gRow,256,0,stream>>>(XB, oW2 + l*16384, nullptr, nullptr, SVl, AGG, nullptr, 1, 0, N);
    k_gemm32<<<gRow,256,0,stream>>>(AGG, oW1 + l*16384, nullptr, nullptr, nullptr, AGG, nullptr, 1, 0, N);
    k_gemm32<<<gRow,256,0,stream>>>(Xl, in2f + l*16384, nullptr, nullptr, nullptr, H, nullptr, 0, 0, N);
    k_zero<<<gN,256,0,stream>>>(HB, (int)NFE);
    k_edge_bwd_t<<<gT16,256,0,stream>>>(H, AGG, Ii, Ij, De, fW1 + l*2560, fb1 + l*128, fW2 + l*16384, fb2 + l*128, DBe, HB, E);
    k_gemm32<<<gRow,256,0,stream>>>(HB, in2f + l*16384, nullptr, XB, nullptr, XB, nullptr, 1, 0, N);
  }
  k_zero<<<(N*3+255)/256,256,0,stream>>>(G, N*3);
  k_zero<<<(M+255)/256,256,0,stream>>>((float*)maxnU, M);
  k_grad<<<gE,256,0,stream>>>(pos, Ii, Ij, De, DBe, G, E);
  k_norm<<<(N+255)/256,256,0,stream>>>(G, mol, maxnU, N);
  k_apply<<<(N+255)/256,256,0,stream>>>(G, mol, maxnU, outF, N);
}

// Round 10
// 5782.284 us; speedup vs baseline: 3.6449x; 3.6449x over previous
//
#include <hip/hip_runtime.h>
#include <cstddef>

// SchNet fwd energy + force bwd, MI355X. Round 10:
//  - coalesced atomic scatter (lane = contiguous f) in both edge kernels
//  - strided c-ownership in bwd (kills 16-way LDS bank conflicts)
//  - cutoff compaction (d >= 5 edges contribute exactly 0; skip them)

#define FD     128
#define NRBF   20
#define CUTF   5.0f
#define PI_F   3.14159265358979f
#define TF     32     // fwd tile edges
#define TB     16     // bwd tile edges
#define PW     136    // u16 pitch (16B-aligned rows, 68 words: spacing 4 mod 32)

typedef unsigned short u16;
typedef unsigned int   u32;

__device__ __forceinline__ float u16f(u16 x){ union{u32 i; float f;} v; v.i=((u32)x)<<16; return v.f; }
__device__ __forceinline__ float blo(u32 u){ union{u32 i; float f;} v; v.i=u<<16; return v.f; }
__device__ __forceinline__ float bhi(u32 u){ union{u32 i; float f;} v; v.i=u&0xffff0000u; return v.f; }
__device__ __forceinline__ u16 f16r(float f){ union{float f; u32 i;} v; v.f=f; u32 r=v.i+0x7fffu+((v.i>>16)&1u); return (u16)(r>>16); }
__device__ __forceinline__ float sspf(float x){ return fmaxf(x,0.f)+log1pf(expf(-fabsf(x)))-0.6931471805599453f; }
__device__ __forceinline__ float sigf(float x){ return 1.f/(1.f+expf(-x)); }
__device__ __forceinline__ float fcutf(float d){ return (d < CUTF) ? 0.5f*(cosf(PI_F*d/CUTF)+1.f) : 0.f; }

__global__ __launch_bounds__(256) void k_zero(float* __restrict__ p, int n){
  int i = blockIdx.x*256 + threadIdx.x;
  if(i < n) p[i] = 0.f;
}

__global__ __launch_bounds__(256) void k_embed(const float* __restrict__ emb, const int* __restrict__ Z,
                                               float* __restrict__ X0, int n){
  int idx = blockIdx.x*256 + threadIdx.x;
  if(idx >= n) return;
  int a = idx >> 7, f = idx & 127;
  X0[idx] = emb[Z[a]*FD + f];
}

__global__ __launch_bounds__(256) void k_edge_geom(const float* __restrict__ pos,
    const int* __restrict__ Ii, const int* __restrict__ Ij,
    float* __restrict__ De, float* __restrict__ DBe, int E){
  int e = blockIdx.x*256 + threadIdx.x;
  if(e >= E) return;
  int i = Ii[e], j = Ij[e];
  float dx = pos[j*3+0]-pos[i*3+0];
  float dy = pos[j*3+1]-pos[i*3+1];
  float dz = pos[j*3+2]-pos[i*3+2];
  De[e] = sqrtf(dx*dx+dy*dy+dz*dz + 1e-12f);
  DBe[e] = 0.f;
}

// active-edge compaction: fc>0 <=> d<CUTF. Inactive edges contribute 0 to fwd+bwd.
__global__ __launch_bounds__(256) void k_compact(const float* __restrict__ De,
    int* __restrict__ EA, int* __restrict__ cnt, int E){
  int e = blockIdx.x*256 + threadIdx.x;
  if(e >= E) return;
  if(De[e] < CUTF){
    int p = atomicAdd(cnt, 1);
    EA[p] = e;
  }
}

// dense GEMM (unchanged, verified)
__global__ __launch_bounds__(256) void k_gemm32(const float* __restrict__ A, const float* __restrict__ B,
    const float* __restrict__ bias, const float* __restrict__ res,
    const float* __restrict__ mul, float* __restrict__ out1, float* __restrict__ out2,
    int transB, int act, int Nr){
  __shared__ float As[64*132];
  const int tid = threadIdx.x;
  const int rb = blockIdx.x * 64;
  for(int q=0;q<8;q++){
    int e = q*256 + tid;
    int r = e >> 5, c = (e & 31) * 4;
    int rr = rb + r; if(rr >= Nr) rr = Nr-1;
    *(float4*)&As[r*132 + c] = *(const float4*)(A + (size_t)rr*FD + c);
  }
  __syncthreads();
  const int r0 = (tid >> 4) * 4;
  const int f0 = (tid & 15) * 8;
  float acc[4][8] = {};
  if(!transB){
    for(int k=0;k<128;k++){
      float a[4] = {As[(r0+0)*132+k], As[(r0+1)*132+k], As[(r0+2)*132+k], As[(r0+3)*132+k]};
      float4 b0 = *(const float4*)(B + k*FD + f0);
      float4 b1 = *(const float4*)(B + k*FD + f0 + 4);
      float b[8] = {b0.x,b0.y,b0.z,b0.w,b1.x,b1.y,b1.z,b1.w};
      #pragma unroll
      for(int i=0;i<4;i++)
        #pragma unroll
        for(int j=0;j<8;j++) acc[i][j] += a[i]*b[j];
    }
  } else {
    for(int k=0;k<128;k++){
      float a[4] = {As[(r0+0)*132+k], As[(r0+1)*132+k], As[(r0+2)*132+k], As[(r0+3)*132+k]};
      float b[8];
      #pragma unroll
      for(int j=0;j<8;j++) b[j] = B[(size_t)(f0+j)*FD + k];
      #pragma unroll
      for(int i=0;i<4;i++)
        #pragma unroll
        for(int j=0;j<8;j++) acc[i][j] += a[i]*b[j];
    }
  }
  float bv[8];
  #pragma unroll
  for(int j=0;j<8;j++) bv[j] = bias ? bias[f0+j] : 0.f;
  #pragma unroll
  for(int rr=0;rr<4;rr++){
    int row = rb + r0 + rr;
    if(row >= Nr) break;
    size_t base = (size_t)row*FD + f0;
    float y[8];
    #pragma unroll
    for(int j=0;j<8;j++) y[j] = acc[rr][j] + bv[j];
    if(res){
      float4 r1 = *(const float4*)(res+base);
      float4 r2 = *(const float4*)(res+base+4);
      y[0]+=r1.x; y[1]+=r1.y; y[2]+=r1.z; y[3]+=r1.w;
      y[4]+=r2.x; y[5]+=r2.y; y[6]+=r2.z; y[7]+=r2.w;
    }
    if(mul){
      float4 m1 = *(const float4*)(mul+base);
      float4 m2 = *(const float4*)(mul+base+4);
      y[0]*=m1.x; y[1]*=m1.y; y[2]*=m1.z; y[3]*=m1.w;
      y[4]*=m2.x; y[5]*=m2.y; y[6]*=m2.z; y[7]*=m2.w;
    }
    if(act){
      *(float4*)(out1+base)   = make_float4(sspf(y[0]),sspf(y[1]),sspf(y[2]),sspf(y[3]));
      *(float4*)(out1+base+4) = make_float4(sspf(y[4]),sspf(y[5]),sspf(y[6]),sspf(y[7]));
      *(float4*)(out2+base)   = make_float4(sigf(y[0]),sigf(y[1]),sigf(y[2]),sigf(y[3]));
      *(float4*)(out2+base+4) = make_float4(sigf(y[4]),sigf(y[5]),sigf(y[6]),sigf(y[7]));
    } else {
      *(float4*)(out1+base)   = make_float4(y[0],y[1],y[2],y[3]);
      *(float4*)(out1+base+4) = make_float4(y[4],y[5],y[6],y[7]);
    }
  }
}

// ---- Edge forward v3: TF=32 compacted edges/block ----
__global__ __launch_bounds__(256) void k_edge_fwd3(
    const float* __restrict__ h,
    const int* __restrict__ Ii, const int* __restrict__ Ij,
    const float* __restrict__ De,
    const int* __restrict__ EA, const int* __restrict__ cnt,
    const float* __restrict__ W1, const float* __restrict__ b1,
    const float* __restrict__ W2, const float* __restrict__ b2,
    float* __restrict__ agg){
  __shared__ u16 sW2[128*PW];
  __shared__ u16 sW1[NRBF*128];
  __shared__ u16 sP [TF*PW];
  __shared__ u16 sWf[TF*128];
  __shared__ int sI[TF], sJ[TF];
  __shared__ float sFc[TF], sDd[TF];
  const int tid = threadIdx.x;
  const int C = *cnt;
  const int base = blockIdx.x*TF;
  if(base >= C) return;
  for(int q=0;q<16;q++){
    int idx = q*256 + tid;
    int c = idx >> 5, f4 = (idx & 31)*4;
    float4 v = *(const float4*)(W2 + c*FD + f4);
    sW2[c*PW+f4+0]=f16r(v.x); sW2[c*PW+f4+1]=f16r(v.y);
    sW2[c*PW+f4+2]=f16r(v.z); sW2[c*PW+f4+3]=f16r(v.w);
  }
  for(int q=0;q<10;q++){ int idx=q*256+tid; sW1[idx]=f16r(W1[idx]); }
  if(tid < TF){
    int idx = base + tid;
    if(idx < C){
      int e = EA[idx];
      sI[tid]=Ii[e]; sJ[tid]=Ij[e];
      float d = De[e];
      sFc[tid]=fcutf(d); sDd[tid]=d;
    } else { sI[tid]=0; sJ[tid]=0; sFc[tid]=0.f; sDd[tid]=1.f; }
  }
  __syncthreads();
  const int t = tid >> 3, oq = tid & 7;
  const float step = CUTF/19.0f;
  const float coef = -0.5f/(step*step);
  { // P[t][c] for c = oq*16..+16
    const float d = sDd[t];
    float rb[NRBF];
    #pragma unroll
    for(int k=0;k<NRBF;k++){ float x = d - step*(float)k; rb[k] = expf(coef*x*x); }
    for(int cc=0; cc<16; cc++){
      int c = oq*16 + cc;
      float tv = b1[c];
      #pragma unroll
      for(int k=0;k<NRBF;k++) tv += rb[k]*u16f(sW1[k*128 + c]);
      sP[t*PW + c] = f16r(sspf(tv));
    }
  }
  __syncthreads();
  { // Wf[t][f] = b2 + P@W2, f = oq*16..+16
    const int f0 = oq*16;
    float wf[16];
    #pragma unroll
    for(int q=0;q<16;q++) wf[q] = b2[f0+q];
    for(int c=0;c<128;c++){
      float p = u16f(sP[t*PW + c]);
      uint4 w0 = *(const uint4*)&sW2[c*PW + f0];
      uint4 w1 = *(const uint4*)&sW2[c*PW + f0 + 8];
      wf[0]+=p*blo(w0.x); wf[1]+=p*bhi(w0.x); wf[2]+=p*blo(w0.y); wf[3]+=p*bhi(w0.y);
      wf[4]+=p*blo(w0.z); wf[5]+=p*bhi(w0.z); wf[6]+=p*blo(w0.w); wf[7]+=p*bhi(w0.w);
      wf[8]+=p*blo(w1.x); wf[9]+=p*bhi(w1.x); wf[10]+=p*blo(w1.y); wf[11]+=p*bhi(w1.y);
      wf[12]+=p*blo(w1.z); wf[13]+=p*bhi(w1.z); wf[14]+=p*blo(w1.w); wf[15]+=p*bhi(w1.w);
    }
    #pragma unroll
    for(int q=0;q<16;q++) sWf[t*128 + f0 + q] = f16r(wf[q]);
  }
  __syncthreads();
  { // coalesced scatter: wave w handles edges t=w*8+s, lane = f
    const int lane = tid & 63, w = tid >> 6;
    for(int s=0;s<8;s++){
      int tt = w*8 + s;
      if(base + tt >= C) continue;
      int i = sI[tt], j = sJ[tt];
      float fc = sFc[tt];
      float h0 = h[(size_t)j*FD + lane];
      float h1 = h[(size_t)j*FD + lane + 64];
      float w0 = u16f(sWf[tt*128 + lane]);
      float w1 = u16f(sWf[tt*128 + lane + 64]);
      atomicAdd(&agg[(size_t)i*FD + lane],      h0*w0*fc);
      atomicAdd(&agg[(size_t)i*FD + lane + 64], h1*w1*fc);
    }
  }
}

// ---- Edge backward v3: TB=16 compacted edges/block, strided c-ownership ----
__global__ __launch_bounds__(256) void k_edge_bwd3(
    const float* __restrict__ h, const float* __restrict__ AB,
    const int* __restrict__ Ii, const int* __restrict__ Ij,
    const float* __restrict__ De,
    const int* __restrict__ EA, const int* __restrict__ cnt,
    const float* __restrict__ W1, const float* __restrict__ b1,
    const float* __restrict__ W2, const float* __restrict__ b2,
    float* __restrict__ DBe, float* __restrict__ HB){
  __shared__ u16 sW2[128*PW];
  __shared__ u16 sW1[NRBF*128];
  __shared__ u16 sPb[TB*PW];    // P -> Wbar
  __shared__ u16 sSt[TB*PW];    // sigma(t) -> tbar
  __shared__ u16 sWf[TB*128];
  __shared__ int sI[TB], sJ[TB], sE[TB];
  __shared__ float sFc[TB], sDd[TB], sfb[TB];
  const int tid = threadIdx.x;
  const int C = *cnt;
  const int base = blockIdx.x*TB;
  if(base >= C) return;
  for(int q=0;q<16;q++){
    int idx = q*256 + tid;
    int c = idx >> 5, f4 = (idx & 31)*4;
    float4 v = *(const float4*)(W2 + c*FD + f4);
    sW2[c*PW+f4+0]=f16r(v.x); sW2[c*PW+f4+1]=f16r(v.y);
    sW2[c*PW+f4+2]=f16r(v.z); sW2[c*PW+f4+3]=f16r(v.w);
  }
  for(int q=0;q<10;q++){ int idx=q*256+tid; sW1[idx]=f16r(W1[idx]); }
  if(tid < TB){
    int idx = base + tid;
    if(idx < C){
      int e = EA[idx];
      sE[tid]=e; sI[tid]=Ii[e]; sJ[tid]=Ij[e];
      float d = De[e];
      sFc[tid]=fcutf(d); sDd[tid]=d;
    } else { sE[tid]=0; sI[tid]=0; sJ[tid]=0; sFc[tid]=0.f; sDd[tid]=1.f; }
  }
  __syncthreads();
  const int t = tid >> 4, oq = tid & 15;
  const bool ok = (base + t < C);
  const float step = CUTF/19.0f;
  const float coef = -0.5f/(step*step);
  { // P & sigma(t) for owned c = oq + 16k (strided)
    const float d = sDd[t];
    float rb[NRBF];
    #pragma unroll
    for(int k=0;k<NRBF;k++){ float x = d - step*(float)k; rb[k] = expf(coef*x*x); }
    #pragma unroll
    for(int k8=0;k8<8;k8++){
      int c = oq + 16*k8;
      float tv = b1[c];
      #pragma unroll
      for(int k=0;k<NRBF;k++) tv += rb[k]*u16f(sW1[k*128 + c]);
      sPb[t*PW + c] = f16r(sspf(tv));
      sSt[t*PW + c] = f16r(sigf(tv));
    }
  }
  __syncthreads();
  { // GEMM1: Wf[t][f] = b2 + P@W2, f = oq*8..+8
    const int f0 = oq*8;
    float wf[8];
    #pragma unroll
    for(int q=0;q<8;q++) wf[q] = b2[f0+q];
    for(int c=0;c<128;c++){
      float p = u16f(sPb[t*PW + c]);
      uint4 w = *(const uint4*)&sW2[c*PW + f0];
      wf[0]+=p*blo(w.x); wf[1]+=p*bhi(w.x); wf[2]+=p*blo(w.y); wf[3]+=p*bhi(w.y);
      wf[4]+=p*blo(w.z); wf[5]+=p*bhi(w.z); wf[6]+=p*blo(w.w); wf[7]+=p*bhi(w.w);
    }
    #pragma unroll
    for(int q=0;q<8;q++) sWf[t*128 + f0 + q] = f16r(wf[q]);
  }
  __syncthreads();
  { // coalesced scatter + Wbar + fbar: wave w handles edges tt=w*4+s, lane=f
    const int lane = tid & 63, w = tid >> 6;
    for(int s=0;s<4;s++){
      int tt = w*4 + s;
      if(base + tt >= C) continue;
      int i = sI[tt], j = sJ[tt];
      float fc = sFc[tt];
      float a0 = AB[(size_t)i*FD + lane];
      float a1 = AB[(size_t)i*FD + lane + 64];
      float h0 = h [(size_t)j*FD + lane];
      float h1 = h [(size_t)j*FD + lane + 64];
      float w0 = u16f(sWf[tt*128 + lane]);
      float w1 = u16f(sWf[tt*128 + lane + 64]);
      atomicAdd(&HB[(size_t)j*FD + lane],      a0*w0*fc);
      atomicAdd(&HB[(size_t)j*FD + lane + 64], a1*w1*fc);
      float g0 = a0*h0, g1 = a1*h1;
      sPb[tt*PW + lane]      = f16r(g0*fc);
      sPb[tt*PW + lane + 64] = f16r(g1*fc);
      float pf = g0*w0 + g1*w1;
      #pragma unroll
      for(int d2=1; d2<64; d2<<=1) pf += __shfl_xor(pf, d2);
      if(lane == 0) sfb[tt] = pf;
    }
  }
  __syncthreads();
  { // GEMM2: Pbar[t][c] = Wbar@W2^T for owned c = oq+16k; tbar = Pbar*sigma in place
    float pb[8] = {};
    for(int f8=0; f8<16; f8++){
      uint4 wb4 = *(const uint4*)&sPb[t*PW + f8*8];
      float wb[8] = {blo(wb4.x),bhi(wb4.x),blo(wb4.y),bhi(wb4.y),blo(wb4.z),bhi(wb4.z),blo(wb4.w),bhi(wb4.w)};
      #pragma unroll
      for(int k8=0;k8<8;k8++){
        int c = oq + 16*k8;
        uint4 w = *(const uint4*)&sW2[c*PW + f8*8];
        pb[k8] += wb[0]*blo(w.x)+wb[1]*bhi(w.x)+wb[2]*blo(w.y)+wb[3]*bhi(w.y)
                + wb[4]*blo(w.z)+wb[5]*bhi(w.z)+wb[6]*blo(w.w)+wb[7]*bhi(w.w);
      }
    }
    #pragma unroll
    for(int k8=0;k8<8;k8++){
      int idx = t*PW + oq + 16*k8;
      sSt[idx] = f16r(pb[k8] * u16f(sSt[idx]));
    }
  }
  { // GEMM3: rbar = tbar@W1^T over owned c; reduce over oq; dbar
    float a20[NRBF] = {};
    #pragma unroll
    for(int k8=0;k8<8;k8++){
      int c = oq + 16*k8;
      float tv = u16f(sSt[t*PW + c]);
      #pragma unroll
      for(int k=0;k<NRBF;k++) a20[k] += tv * u16f(sW1[k*128 + c]);
    }
    #pragma unroll
    for(int k=0;k<NRBF;k++){
      a20[k] += __shfl_xor(a20[k],1); a20[k] += __shfl_xor(a20[k],2);
      a20[k] += __shfl_xor(a20[k],4); a20[k] += __shfl_xor(a20[k],8);
    }
    if(oq == 0 && ok){
      const float d = sDd[t];
      float drb = 0.f;
      #pragma unroll
      for(int k=0;k<NRBF;k++){
        float x = d - step*(float)k;
        float rbv = expf(coef*x*x);
        drb += a20[k] * rbv * 2.f*coef*x;
      }
      float dfc = (d < CUTF) ? (-0.5f*(PI_F/CUTF)*sinf(PI_F*d/CUTF)) : 0.f;
      DBe[sE[t]] += drb + sfb[t]*dfc;
    }
  }
}

// fused atomwise head + head-backward (unchanged, verified)
__global__ __launch_bounds__(256) void k_head(const float* __restrict__ X3,
    const float* __restrict__ aW1, const float* __restrict__ ab1,
    const float* __restrict__ aW2, const float* __restrict__ ab2,
    const int* __restrict__ mol, float* __restrict__ Emol, float* __restrict__ XB, int N){
  __shared__ float sx[64*129];
  __shared__ float sg[64*65];
  const int tid = threadIdx.x;
  const int base = blockIdx.x*64;
  for(int q=0;q<8;q++){
    int ee = q*256 + tid;
    int r = ee >> 5, c = (ee & 31)*4;
    int row = base + r; if(row >= N) row = N-1;
    float4 v = *(const float4*)(X3 + (size_t)row*FD + c);
    sx[r*129 + c+0] = v.x; sx[r*129 + c+1] = v.y;
    sx[r*129 + c+2] = v.z; sx[r*129 + c+3] = v.w;
  }
  __syncthreads();
  {
    const int a = tid >> 2, q = tid & 3;
    float pe = 0.f;
    for(int cc=0; cc<16; cc++){
      int c = q*16 + cc;
      float u = ab1[c];
      for(int f=0; f<128; f++) u += sx[a*129 + f]*aW1[f*64 + c];
      pe += sspf(u)*aW2[c];
      sg[a*65 + c] = sigf(u)*aW2[c];
    }
    pe += __shfl_xor(pe, 1);
    pe += __shfl_xor(pe, 2);
    if(q == 0 && base + a < N) atomicAdd(&Emol[mol[base + a]], pe + ab2[0]);
  }
  __syncthreads();
  {
    const int f = tid & 127, g2 = tid >> 7;
    float acc[32];
    #pragma unroll
    for(int q=0;q<32;q++) acc[q]=0.f;
    for(int c=0;c<64;c++){
      float w = aW1[f*64 + c];
      #pragma unroll
      for(int q=0;q<32;q++) acc[q] += sg[(g2*32+q)*65 + c]*w;
    }
    #pragma unroll
    for(int q=0;q<32;q++){
      int row = base + g2*32 + q;
      if(row < N) XB[(size_t)row*FD + f] = acc[q];
    }
  }
}

__global__ __launch_bounds__(256) void k_grad(const float* __restrict__ pos,
    const int* __restrict__ Ii, const int* __restrict__ Ij,
    const float* __restrict__ De, const float* __restrict__ DBe,
    const int* __restrict__ EA, const int* __restrict__ cnt,
    float* __restrict__ G){
  int idx = blockIdx.x*256 + threadIdx.x;
  if(idx >= *cnt) return;
  int e = EA[idx];
  float s = DBe[e] / De[e];
  int i = Ii[e], j = Ij[e];
  float dx = s*(pos[i*3+0]-pos[j*3+0]);
  float dy = s*(pos[i*3+1]-pos[j*3+1]);
  float dz = s*(pos[i*3+2]-pos[j*3+2]);
  atomicAdd(&G[i*3+0], dx); atomicAdd(&G[i*3+1], dy); atomicAdd(&G[i*3+2], dz);
  atomicAdd(&G[j*3+0], -dx); atomicAdd(&G[j*3+1], -dy); atomicAdd(&G[j*3+2], -dz);
}

__global__ __launch_bounds__(256) void k_norm(const float* __restrict__ G,
    const int* __restrict__ mol, u32* __restrict__ maxnU, int N){
  int n = blockIdx.x*256 + threadIdx.x;
  if(n >= N) return;
  float ax = G[n*3], ay = G[n*3+1], az = G[n*3+2];
  float nrm = sqrtf(ax*ax+ay*ay+az*az);
  atomicMax(&maxnU[mol[n]], __float_as_uint(nrm));
}

__global__ __launch_bounds__(256) void k_apply(const float* __restrict__ G,
    const int* __restrict__ mol, const u32* __restrict__ maxnU,
    float* __restrict__ outA, int N){
  int n = blockIdx.x*256 + threadIdx.x;
  if(n >= N) return;
  float mx = __uint_as_float(maxnU[mol[n]]);
  float coefc = fminf(1.0f/fmaxf(mx, 1e-8f), 1.0f);
  outA[n*3+0] = -G[n*3+0]*coefc;
  outA[n*3+1] = -G[n*3+1]*coefc;
  outA[n*3+2] = -G[n*3+2]*coefc;
}

extern "C" void kernel_launch(void* const* d_in, const int* in_sizes, int n_in,
                              void* d_out, int out_size, void* d_ws, size_t ws_size,
                              hipStream_t stream) {
  (void)n_in;
  const float* pos  = (const float*)d_in[0];
  const float* emb  = (const float*)d_in[1];
  const float* in2f = (const float*)d_in[2];
  const float* fW1  = (const float*)d_in[3];
  const float* fb1  = (const float*)d_in[4];
  const float* fW2  = (const float*)d_in[5];
  const float* fb2  = (const float*)d_in[6];
  const float* oW1  = (const float*)d_in[7];
  const float* ob1  = (const float*)d_in[8];
  const float* oW2  = (const float*)d_in[9];
  const float* ob2  = (const float*)d_in[10];
  const float* aW1  = (const float*)d_in[11];
  const float* ab1  = (const float*)d_in[12];
  const float* aW2  = (const float*)d_in[13];
  const float* ab2  = (const float*)d_in[14];
  const int*   Z    = (const int*)d_in[15];
  const int*   Ii   = (const int*)d_in[16];
  const int*   Ij   = (const int*)d_in[17];
  const int*   mol  = (const int*)d_in[18];
  const int N = in_sizes[15];
  const int E = in_sizes[16];
  const int M = out_size - N*3;
  const size_t NFE = (size_t)N*FD;
  float* outF = (float*)d_out;
  float* outE = outF + (size_t)N*3;
  float* ws = (float*)d_ws;
  if(ws_size < (11*NFE + 3*(size_t)E + 16)*4) return;   // R5 proved 11NFE+3E fits

  float* X0  = ws;
  float* SV0 = ws + 4*NFE;
  float* H   = ws + 7*NFE;
  float* AGG = ws + 8*NFE;
  float* XB  = ws + 9*NFE;
  float* HB  = ws + 10*NFE;
  float* De  = ws + 11*NFE;
  float* DBe = De + E;
  int*   EA  = (int*)(DBe + E);
  int*   cnt = EA + E;
  float* G    = AGG;
  u32*  maxnU = (u32*)H;

  const int gN   = (int)((NFE + 255)/256);
  const int gE   = (E + 255)/256;
  const int gTF  = (E + TF-1)/TF;
  const int gTB  = (E + TB-1)/TB;
  const int gRow = (N + 63)/64;

  k_embed<<<gN,256,0,stream>>>(emb, Z, X0, (int)NFE);
  k_edge_geom<<<gE,256,0,stream>>>(pos, Ii, Ij, De, DBe, E);
  k_zero<<<1,256,0,stream>>>((float*)cnt, 1);
  k_compact<<<gE,256,0,stream>>>(De, EA, cnt, E);
  for(int l=0;l<3;l++){
    float* Xl  = X0 + (size_t)l*NFE;
    float* Xn  = X0 + (size_t)(l+1)*NFE;
    float* SVl = SV0 + (size_t)l*NFE;
    k_gemm32<<<gRow,256,0,stream>>>(Xl, in2f + l*16384, nullptr, nullptr, nullptr, H, nullptr, 0, 0, N);
    k_zero<<<gN,256,0,stream>>>(AGG, (int)NFE);
    k_edge_fwd3<<<gTF,256,0,stream>>>(H, Ii, Ij, De, EA, cnt, fW1 + l*2560, fb1 + l*128, fW2 + l*16384, fb2 + l*128, AGG);
    k_gemm32<<<gRow,256,0,stream>>>(AGG, oW1 + l*16384, ob1 + l*128, nullptr, nullptr, H, SVl, 0, 1, N);
    k_gemm32<<<gRow,256,0,stream>>>(H, oW2 + l*16384, ob2 + l*128, Xl, nullptr, Xn, nullptr, 0, 0, N);
  }
  k_zero<<<(M+255)/256,256,0,stream>>>(outE, M);
  k_head<<<gRow,256,0,stream>>>(X0 + 3*NFE, aW1, ab1, aW2, ab2, mol, outE, XB, N);
  for(int l=2;l>=0;l--){
    float* Xl  = X0 + (size_t)l*NFE;
    float* SVl = SV0 + (size_t)l*NFE;
    k_gemm32<<<gRow,256,0,stream>>>(XB, oW2 + l*16384, nullptr, nullptr, SVl, AGG, nullptr, 1, 0, N);
    k_gemm32<<<gRow,256,0,stream>>>(AGG, oW1 + l*16384, nullptr, nullptr, nullptr, AGG, nullptr, 1, 0, N);
    k_gemm32<<<gRow,256,0,stream>>>(Xl, in2f + l*16384, nullptr, nullptr, nullptr, H, nullptr, 0, 0, N);
    k_zero<<<gN,256,0,stream>>>(HB, (int)NFE);
    k_edge_bwd3<<<gTB,256,0,stream>>>(H, AGG, Ii, Ij, De, EA, cnt, fW1 + l*2560, fb1 + l*128, fW2 + l*16384, fb2 + l*128, DBe, HB);
    k_gemm32<<<gRow,256,0,stream>>>(HB, in2f + l*16384, nullptr, XB, nullptr, XB, nullptr, 1, 0, N);
  }
  k_zero<<<(N*3+255)/256,256,0,stream>>>(G, N*3);
  k_zero<<<(M+255)/256,256,0,stream>>>((float*)maxnU, M);
  k_grad<<<gE,256,0,stream>>>(pos, Ii, Ij, De, DBe, EA, cnt, G);
  k_norm<<<(N+255)/256,256,0,stream>>>(G, mol, maxnU, N);
  k_apply<<<(N+255)/256,256,0,stream>>>(G, mol, maxnU, outF, N);
}

// Round 11
// 5039.843 us; speedup vs baseline: 4.1819x; 1.1473x over previous
//
#include <hip/hip_runtime.h>
#include <cstddef>

// SchNet fwd energy + force bwd, MI355X. Round 11: MFMA tile GEMMs in edge
// kernels (16x16x32 bf16). R10's coalesced scatter + compaction retained.

#define FD     128
#define NRBF   20
#define CUTF   5.0f
#define PI_F   3.14159265358979f
#define TF     32     // fwd tile edges
#define TB     16     // bwd tile edges
#define PW     136    // u16 pitch (272 B rows: 16B-aligned, 68 words -> 4 mod 32 banks)

typedef unsigned short u16;
typedef unsigned int   u32;
typedef __attribute__((ext_vector_type(8))) short bf16x8;
typedef __attribute__((ext_vector_type(4))) float f32x4;

__device__ __forceinline__ float u16f(u16 x){ union{u32 i; float f;} v; v.i=((u32)x)<<16; return v.f; }
__device__ __forceinline__ float blo(u32 u){ union{u32 i; float f;} v; v.i=u<<16; return v.f; }
__device__ __forceinline__ float bhi(u32 u){ union{u32 i; float f;} v; v.i=u&0xffff0000u; return v.f; }
__device__ __forceinline__ u16 f16r(float f){ union{float f; u32 i;} v; v.f=f; u32 r=v.i+0x7fffu+((v.i>>16)&1u); return (u16)(r>>16); }
__device__ __forceinline__ float sspf(float x){ return fmaxf(x,0.f)+log1pf(expf(-fabsf(x)))-0.6931471805599453f; }
__device__ __forceinline__ float sigf(float x){ return 1.f/(1.f+expf(-x)); }
__device__ __forceinline__ float fcutf(float d){ return (d < CUTF) ? 0.5f*(cosf(PI_F*d/CUTF)+1.f) : 0.f; }

__global__ __launch_bounds__(256) void k_zero(float* __restrict__ p, int n){
  int i = blockIdx.x*256 + threadIdx.x;
  if(i < n) p[i] = 0.f;
}

__global__ __launch_bounds__(256) void k_embed(const float* __restrict__ emb, const int* __restrict__ Z,
                                               float* __restrict__ X0, int n){
  int idx = blockIdx.x*256 + threadIdx.x;
  if(idx >= n) return;
  int a = idx >> 7, f = idx & 127;
  X0[idx] = emb[Z[a]*FD + f];
}

__global__ __launch_bounds__(256) void k_edge_geom(const float* __restrict__ pos,
    const int* __restrict__ Ii, const int* __restrict__ Ij,
    float* __restrict__ De, float* __restrict__ DBe, int E){
  int e = blockIdx.x*256 + threadIdx.x;
  if(e >= E) return;
  int i = Ii[e], j = Ij[e];
  float dx = pos[j*3+0]-pos[i*3+0];
  float dy = pos[j*3+1]-pos[i*3+1];
  float dz = pos[j*3+2]-pos[i*3+2];
  De[e] = sqrtf(dx*dx+dy*dy+dz*dz + 1e-12f);
  DBe[e] = 0.f;
}

__global__ __launch_bounds__(256) void k_compact(const float* __restrict__ De,
    int* __restrict__ EA, int* __restrict__ cnt, int E){
  int e = blockIdx.x*256 + threadIdx.x;
  if(e >= E) return;
  if(De[e] < CUTF){
    int p = atomicAdd(cnt, 1);
    EA[p] = e;
  }
}

// dense GEMM (unchanged, verified)
__global__ __launch_bounds__(256) void k_gemm32(const float* __restrict__ A, const float* __restrict__ B,
    const float* __restrict__ bias, const float* __restrict__ res,
    const float* __restrict__ mul, float* __restrict__ out1, float* __restrict__ out2,
    int transB, int act, int Nr){
  __shared__ float As[64*132];
  const int tid = threadIdx.x;
  const int rb = blockIdx.x * 64;
  for(int q=0;q<8;q++){
    int e = q*256 + tid;
    int r = e >> 5, c = (e & 31) * 4;
    int rr = rb + r; if(rr >= Nr) rr = Nr-1;
    *(float4*)&As[r*132 + c] = *(const float4*)(A + (size_t)rr*FD + c);
  }
  __syncthreads();
  const int r0 = (tid >> 4) * 4;
  const int f0 = (tid & 15) * 8;
  float acc[4][8] = {};
  if(!transB){
    for(int k=0;k<128;k++){
      float a[4] = {As[(r0+0)*132+k], As[(r0+1)*132+k], As[(r0+2)*132+k], As[(r0+3)*132+k]};
      float4 b0 = *(const float4*)(B + k*FD + f0);
      float4 b1 = *(const float4*)(B + k*FD + f0 + 4);
      float b[8] = {b0.x,b0.y,b0.z,b0.w,b1.x,b1.y,b1.z,b1.w};
      #pragma unroll
      for(int i=0;i<4;i++)
        #pragma unroll
        for(int j=0;j<8;j++) acc[i][j] += a[i]*b[j];
    }
  } else {
    for(int k=0;k<128;k++){
      float a[4] = {As[(r0+0)*132+k], As[(r0+1)*132+k], As[(r0+2)*132+k], As[(r0+3)*132+k]};
      float b[8];
      #pragma unroll
      for(int j=0;j<8;j++) b[j] = B[(size_t)(f0+j)*FD + k];
      #pragma unroll
      for(int i=0;i<4;i++)
        #pragma unroll
        for(int j=0;j<8;j++) acc[i][j] += a[i]*b[j];
    }
  }
  float bv[8];
  #pragma unroll
  for(int j=0;j<8;j++) bv[j] = bias ? bias[f0+j] : 0.f;
  #pragma unroll
  for(int rr=0;rr<4;rr++){
    int row = rb + r0 + rr;
    if(row >= Nr) break;
    size_t base = (size_t)row*FD + f0;
    float y[8];
    #pragma unroll
    for(int j=0;j<8;j++) y[j] = acc[rr][j] + bv[j];
    if(res){
      float4 r1 = *(const float4*)(res+base);
      float4 r2 = *(const float4*)(res+base+4);
      y[0]+=r1.x; y[1]+=r1.y; y[2]+=r1.z; y[3]+=r1.w;
      y[4]+=r2.x; y[5]+=r2.y; y[6]+=r2.z; y[7]+=r2.w;
    }
    if(mul){
      float4 m1 = *(const float4*)(mul+base);
      float4 m2 = *(const float4*)(mul+base+4);
      y[0]*=m1.x; y[1]*=m1.y; y[2]*=m1.z; y[3]*=m1.w;
      y[4]*=m2.x; y[5]*=m2.y; y[6]*=m2.z; y[7]*=m2.w;
    }
    if(act){
      *(float4*)(out1+base)   = make_float4(sspf(y[0]),sspf(y[1]),sspf(y[2]),sspf(y[3]));
      *(float4*)(out1+base+4) = make_float4(sspf(y[4]),sspf(y[5]),sspf(y[6]),sspf(y[7]));
      *(float4*)(out2+base)   = make_float4(sigf(y[0]),sigf(y[1]),sigf(y[2]),sigf(y[3]));
      *(float4*)(out2+base+4) = make_float4(sigf(y[4]),sigf(y[5]),sigf(y[6]),sigf(y[7]));
    } else {
      *(float4*)(out1+base)   = make_float4(y[0],y[1],y[2],y[3]);
      *(float4*)(out1+base+4) = make_float4(y[4],y[5],y[6],y[7]);
    }
  }
}

// ---- Edge forward v4: TF=32 edges/block, MFMA Wf = P@W2 ----
__global__ __launch_bounds__(256) void k_edge_fwd4(
    const float* __restrict__ h,
    const int* __restrict__ Ii, const int* __restrict__ Ij,
    const float* __restrict__ De,
    const int* __restrict__ EA, const int* __restrict__ cnt,
    const float* __restrict__ W1, const float* __restrict__ b1,
    const float* __restrict__ W2, const float* __restrict__ b2,
    float* __restrict__ agg){
  __shared__ u16 sW2T[128*PW];   // W2^T [f][c]
  __shared__ u16 sW1[NRBF*128];
  __shared__ u16 sP [TF*PW];     // P [e][c]
  __shared__ u16 sWf[TF*PW];     // Wf [e][f]
  __shared__ float srbf[TF*NRBF];
  __shared__ int sI[TF], sJ[TF];
  __shared__ float sFc[TF], sDd[TF];
  const int tid = threadIdx.x;
  const int C = *cnt;
  const int base = blockIdx.x*TF;
  if(base >= C) return;
  for(int q=0;q<16;q++){
    int idx = q*256 + tid;
    int c = idx >> 5, f4 = (idx & 31)*4;
    float4 v = *(const float4*)(W2 + c*FD + f4);
    sW2T[(f4+0)*PW + c] = f16r(v.x);
    sW2T[(f4+1)*PW + c] = f16r(v.y);
    sW2T[(f4+2)*PW + c] = f16r(v.z);
    sW2T[(f4+3)*PW + c] = f16r(v.w);
  }
  for(int q=0;q<10;q++){ int idx=q*256+tid; sW1[idx]=f16r(W1[idx]); }
  if(tid < TF){
    int idx = base + tid;
    if(idx < C){
      int e = EA[idx];
      sI[tid]=Ii[e]; sJ[tid]=Ij[e];
      float d = De[e];
      sFc[tid]=fcutf(d); sDd[tid]=d;
    } else { sI[tid]=0; sJ[tid]=0; sFc[tid]=0.f; sDd[tid]=1.f; }
  }
  __syncthreads();
  const float step = CUTF/19.0f;
  const float coef = -0.5f/(step*step);
  for(int idx=tid; idx<TF*NRBF; idx+=256){
    int t = idx/NRBF, k = idx%NRBF;
    float x = sDd[t] - step*(float)k;
    srbf[idx] = expf(coef*x*x);
  }
  __syncthreads();
  { // P[t][c], 8 threads/edge, strided c
    const int t = tid >> 3, oq = tid & 7;
    #pragma unroll
    for(int kk=0; kk<16; kk++){
      int c = oq + 8*kk;
      float tv = b1[c];
      #pragma unroll
      for(int k=0;k<NRBF;k++) tv += srbf[t*NRBF+k]*u16f(sW1[k*128 + c]);
      sP[t*PW + c] = f16r(sspf(tv));
    }
  }
  __syncthreads();
  { // MFMA: Wf[e][f] = P@W2 + b2;  A=P[e][c], B[k=c][n=f]=sW2T rows
    const int w = tid >> 6, lane = tid & 63;
    const int quad = lane >> 4, l16 = lane & 15;
    const int mt = w >> 1;
    #pragma unroll
    for(int p=0;p<4;p++){
      const int nt = (w&1)*4 + p;
      f32x4 acc = {0.f,0.f,0.f,0.f};
      #pragma unroll
      for(int ks=0;ks<4;ks++){
        bf16x8 a = *(const bf16x8*)&sP  [(mt*16+l16)*PW + ks*32 + quad*8];
        bf16x8 b = *(const bf16x8*)&sW2T[(nt*16+l16)*PW + ks*32 + quad*8];
        acc = __builtin_amdgcn_mfma_f32_16x16x32_bf16(a,b,acc,0,0,0);
      }
      float bb = b2[nt*16 + l16];
      #pragma unroll
      for(int r=0;r<4;r++)
        sWf[(mt*16+quad*4+r)*PW + nt*16+l16] = f16r(acc[r] + bb);
    }
  }
  __syncthreads();
  { // coalesced scatter
    const int lane = tid & 63, w = tid >> 6;
    for(int s=0;s<8;s++){
      int tt = w*8 + s;
      if(base + tt >= C) continue;
      int i = sI[tt], j = sJ[tt];
      float fc = sFc[tt];
      float h0 = h[(size_t)j*FD + lane];
      float h1 = h[(size_t)j*FD + lane + 64];
      float w0 = u16f(sWf[tt*PW + lane]);
      float w1 = u16f(sWf[tt*PW + lane + 64]);
      atomicAdd(&agg[(size_t)i*FD + lane],      h0*w0*fc);
      atomicAdd(&agg[(size_t)i*FD + lane + 64], h1*w1*fc);
    }
  }
}

// ---- Edge backward v4: TB=16 edges/block, MFMA GEMM1+GEMM2 ----
__global__ __launch_bounds__(256) void k_edge_bwd4(
    const float* __restrict__ h, const float* __restrict__ AB,
    const int* __restrict__ Ii, const int* __restrict__ Ij,
    const float* __restrict__ De,
    const int* __restrict__ EA, const int* __restrict__ cnt,
    const float* __restrict__ W1, const float* __restrict__ b1,
    const float* __restrict__ W2, const float* __restrict__ b2,
    float* __restrict__ DBe, float* __restrict__ HB){
  __shared__ u16 sW2X[128*PW];   // W2^T [f][c] first, then restaged W2 [c][f]
  __shared__ u16 sW1[NRBF*128];
  __shared__ u16 sP [TB*PW];     // P [e][c] -> Wbar [e][f]
  __shared__ u16 sSt[TB*PW];     // sigma(t) -> tbar
  __shared__ u16 sWf[TB*PW];
  __shared__ float srbf[TB*NRBF];
  __shared__ int sI[TB], sJ[TB], sE[TB];
  __shared__ float sFc[TB], sDd[TB], sfb[TB];
  const int tid = threadIdx.x;
  const int C = *cnt;
  const int base = blockIdx.x*TB;
  if(base >= C) return;
  for(int q=0;q<16;q++){
    int idx = q*256 + tid;
    int c = idx >> 5, f4 = (idx & 31)*4;
    float4 v = *(const float4*)(W2 + c*FD + f4);
    sW2X[(f4+0)*PW + c] = f16r(v.x);
    sW2X[(f4+1)*PW + c] = f16r(v.y);
    sW2X[(f4+2)*PW + c] = f16r(v.z);
    sW2X[(f4+3)*PW + c] = f16r(v.w);
  }
  for(int q=0;q<10;q++){ int idx=q*256+tid; sW1[idx]=f16r(W1[idx]); }
  if(tid < TB){
    int idx = base + tid;
    if(idx < C){
      int e = EA[idx];
      sE[tid]=e; sI[tid]=Ii[e]; sJ[tid]=Ij[e];
      float d = De[e];
      sFc[tid]=fcutf(d); sDd[tid]=d;
    } else { sE[tid]=0; sI[tid]=0; sJ[tid]=0; sFc[tid]=0.f; sDd[tid]=1.f; }
  }
  __syncthreads();
  const float step = CUTF/19.0f;
  const float coef = -0.5f/(step*step);
  for(int idx=tid; idx<TB*NRBF; idx+=256){
    int t = idx/NRBF, k = idx%NRBF;
    float x = sDd[t] - step*(float)k;
    srbf[idx] = expf(coef*x*x);
  }
  __syncthreads();
  { // P & sigma(t): 16 threads/edge, strided c
    const int t = tid >> 4, oq = tid & 15;
    #pragma unroll
    for(int k8=0;k8<8;k8++){
      int c = oq + 16*k8;
      float tv = b1[c];
      #pragma unroll
      for(int k=0;k<NRBF;k++) tv += srbf[t*NRBF+k]*u16f(sW1[k*128 + c]);
      sP [t*PW + c] = f16r(sspf(tv));
      sSt[t*PW + c] = f16r(sigf(tv));
    }
  }
  __syncthreads();
  const int w = tid >> 6, lane = tid & 63;
  const int quad = lane >> 4, l16 = lane & 15;
  { // GEMM1 MFMA: Wf[e][f] = P@W2 + b2
    #pragma unroll
    for(int p=0;p<2;p++){
      const int nt = w*2 + p;
      f32x4 acc = {0.f,0.f,0.f,0.f};
      #pragma unroll
      for(int ks=0;ks<4;ks++){
        bf16x8 a = *(const bf16x8*)&sP  [l16*PW + ks*32 + quad*8];
        bf16x8 b = *(const bf16x8*)&sW2X[(nt*16+l16)*PW + ks*32 + quad*8];
        acc = __builtin_amdgcn_mfma_f32_16x16x32_bf16(a,b,acc,0,0,0);
      }
      float bb = b2[nt*16 + l16];
      #pragma unroll
      for(int r=0;r<4;r++)
        sWf[(quad*4+r)*PW + nt*16+l16] = f16r(acc[r] + bb);
    }
  }
  __syncthreads();
  { // scatter + Wbar (overwrites sP) + fbar
    for(int s=0;s<4;s++){
      int tt = w*4 + s;
      if(base + tt >= C) continue;
      int i = sI[tt], j = sJ[tt];
      float fc = sFc[tt];
      float a0 = AB[(size_t)i*FD + lane];
      float a1 = AB[(size_t)i*FD + lane + 64];
      float h0 = h [(size_t)j*FD + lane];
      float h1 = h [(size_t)j*FD + lane + 64];
      float w0 = u16f(sWf[tt*PW + lane]);
      float w1 = u16f(sWf[tt*PW + lane + 64]);
      atomicAdd(&HB[(size_t)j*FD + lane],      a0*w0*fc);
      atomicAdd(&HB[(size_t)j*FD + lane + 64], a1*w1*fc);
      float g0 = a0*h0, g1 = a1*h1;
      sP[tt*PW + lane]      = f16r(g0*fc);
      sP[tt*PW + lane + 64] = f16r(g1*fc);
      float pf = g0*w0 + g1*w1;
      #pragma unroll
      for(int d2=1; d2<64; d2<<=1) pf += __shfl_xor(pf, d2);
      if(lane == 0) sfb[tt] = pf;
    }
  }
  __syncthreads();
  { // restage W2 row-major [c][f] into sW2X
    for(int q=0;q<16;q++){
      int idx = q*256 + tid;
      int c = idx >> 5, f4 = (idx & 31)*4;
      float4 v = *(const float4*)(W2 + c*FD + f4);
      sW2X[c*PW+f4+0]=f16r(v.x); sW2X[c*PW+f4+1]=f16r(v.y);
      sW2X[c*PW+f4+2]=f16r(v.z); sW2X[c*PW+f4+3]=f16r(v.w);
    }
  }
  __syncthreads();
  { // GEMM2 MFMA: Pbar[e][c] = Wbar@W2^T ; tbar = Pbar*sigma in place
    #pragma unroll
    for(int p=0;p<2;p++){
      const int nt = w*2 + p;
      f32x4 acc = {0.f,0.f,0.f,0.f};
      #pragma unroll
      for(int ks=0;ks<4;ks++){
        bf16x8 a = *(const bf16x8*)&sP  [l16*PW + ks*32 + quad*8];
        bf16x8 b = *(const bf16x8*)&sW2X[(nt*16+l16)*PW + ks*32 + quad*8];
        acc = __builtin_amdgcn_mfma_f32_16x16x32_bf16(a,b,acc,0,0,0);
      }
      #pragma unroll
      for(int r=0;r<4;r++){
        int idx = (quad*4+r)*PW + nt*16+l16;
        sSt[idx] = f16r(acc[r] * u16f(sSt[idx]));
      }
    }
  }
  __syncthreads();
  { // GEMM3 (VALU): rbar = tbar@W1^T over strided c; reduce; dbar
    const int t = tid >> 4, oq = tid & 15;
    const bool ok = (base + t < C);
    float a20[NRBF] = {};
    #pragma unroll
    for(int k8=0;k8<8;k8++){
      int c = oq + 16*k8;
      float tv = u16f(sSt[t*PW + c]);
      #pragma unroll
      for(int k=0;k<NRBF;k++) a20[k] += tv * u16f(sW1[k*128 + c]);
    }
    #pragma unroll
    for(int k=0;k<NRBF;k++){
      a20[k] += __shfl_xor(a20[k],1); a20[k] += __shfl_xor(a20[k],2);
      a20[k] += __shfl_xor(a20[k],4); a20[k] += __shfl_xor(a20[k],8);
    }
    if(oq == 0 && ok){
      const float d = sDd[t];
      float drb = 0.f;
      #pragma unroll
      for(int k=0;k<NRBF;k++){
        float x = d - step*(float)k;
        drb += a20[k] * srbf[t*NRBF+k] * 2.f*coef*x;
      }
      float dfc = (d < CUTF) ? (-0.5f*(PI_F/CUTF)*sinf(PI_F*d/CUTF)) : 0.f;
      DBe[sE[t]] += drb + sfb[t]*dfc;
    }
  }
}

// fused atomwise head + head-backward (unchanged, verified)
__global__ __launch_bounds__(256) void k_head(const float* __restrict__ X3,
    const float* __restrict__ aW1, const float* __restrict__ ab1,
    const float* __restrict__ aW2, const float* __restrict__ ab2,
    const int* __restrict__ mol, float* __restrict__ Emol, float* __restrict__ XB, int N){
  __shared__ float sx[64*129];
  __shared__ float sg[64*65];
  const int tid = threadIdx.x;
  const int base = blockIdx.x*64;
  for(int q=0;q<8;q++){
    int ee = q*256 + tid;
    int r = ee >> 5, c = (ee & 31)*4;
    int row = base + r; if(row >= N) row = N-1;
    float4 v = *(const float4*)(X3 + (size_t)row*FD + c);
    sx[r*129 + c+0] = v.x; sx[r*129 + c+1] = v.y;
    sx[r*129 + c+2] = v.z; sx[r*129 + c+3] = v.w;
  }
  __syncthreads();
  {
    const int a = tid >> 2, q = tid & 3;
    float pe = 0.f;
    for(int cc=0; cc<16; cc++){
      int c = q*16 + cc;
      float u = ab1[c];
      for(int f=0; f<128; f++) u += sx[a*129 + f]*aW1[f*64 + c];
      pe += sspf(u)*aW2[c];
      sg[a*65 + c] = sigf(u)*aW2[c];
    }
    pe += __shfl_xor(pe, 1);
    pe += __shfl_xor(pe, 2);
    if(q == 0 && base + a < N) atomicAdd(&Emol[mol[base + a]], pe + ab2[0]);
  }
  __syncthreads();
  {
    const int f = tid & 127, g2 = tid >> 7;
    float acc[32];
    #pragma unroll
    for(int q=0;q<32;q++) acc[q]=0.f;
    for(int c=0;c<64;c++){
      float w = aW1[f*64 + c];
      #pragma unroll
      for(int q=0;q<32;q++) acc[q] += sg[(g2*32+q)*65 + c]*w;
    }
    #pragma unroll
    for(int q=0;q<32;q++){
      int row = base + g2*32 + q;
      if(row < N) XB[(size_t)row*FD + f] = acc[q];
    }
  }
}

__global__ __launch_bounds__(256) void k_grad(const float* __restrict__ pos,
    const int* __restrict__ Ii, const int* __restrict__ Ij,
    const float* __restrict__ De, const float* __restrict__ DBe,
    const int* __restrict__ EA, const int* __restrict__ cnt,
    float* __restrict__ G){
  int idx = blockIdx.x*256 + threadIdx.x;
  if(idx >= *cnt) return;
  int e = EA[idx];
  float s = DBe[e] / De[e];
  int i = Ii[e], j = Ij[e];
  float dx = s*(pos[i*3+0]-pos[j*3+0]);
  float dy = s*(pos[i*3+1]-pos[j*3+1]);
  float dz = s*(pos[i*3+2]-pos[j*3+2]);
  atomicAdd(&G[i*3+0], dx); atomicAdd(&G[i*3+1], dy); atomicAdd(&G[i*3+2], dz);
  atomicAdd(&G[j*3+0], -dx); atomicAdd(&G[j*3+1], -dy); atomicAdd(&G[j*3+2], -dz);
}

__global__ __launch_bounds__(256) void k_norm(const float* __restrict__ G,
    const int* __restrict__ mol, u32* __restrict__ maxnU, int N){
  int n = blockIdx.x*256 + threadIdx.x;
  if(n >= N) return;
  float ax = G[n*3], ay = G[n*3+1], az = G[n*3+2];
  float nrm = sqrtf(ax*ax+ay*ay+az*az);
  atomicMax(&maxnU[mol[n]], __float_as_uint(nrm));
}

__global__ __launch_bounds__(256) void k_apply(const float* __restrict__ G,
    const int* __restrict__ mol, const u32* __restrict__ maxnU,
    float* __restrict__ outA, int N){
  int n = blockIdx.x*256 + threadIdx.x;
  if(n >= N) return;
  float mx = __uint_as_float(maxnU[mol[n]]);
  float coefc = fminf(1.0f/fmaxf(mx, 1e-8f), 1.0f);
  outA[n*3+0] = -G[n*3+0]*coefc;
  outA[n*3+1] = -G[n*3+1]*coefc;
  outA[n*3+2] = -G[n*3+2]*coefc;
}

extern "C" void kernel_launch(void* const* d_in, const int* in_sizes, int n_in,
                              void* d_out, int out_size, void* d_ws, size_t ws_size,
                              hipStream_t stream) {
  (void)n_in;
  const float* pos  = (const float*)d_in[0];
  const float* emb  = (const float*)d_in[1];
  const float* in2f = (const float*)d_in[2];
  const float* fW1  = (const float*)d_in[3];
  const float* fb1  = (const float*)d_in[4];
  const float* fW2  = (const float*)d_in[5];
  const float* fb2  = (const float*)d_in[6];
  const float* oW1  = (const float*)d_in[7];
  const float* ob1  = (const float*)d_in[8];
  const float* oW2  = (const float*)d_in[9];
  const float* ob2  = (const float*)d_in[10];
  const float* aW1  = (const float*)d_in[11];
  const float* ab1  = (const float*)d_in[12];
  const float* aW2  = (const float*)d_in[13];
  const float* ab2  = (const float*)d_in[14];
  const int*   Z    = (const int*)d_in[15];
  const int*   Ii   = (const int*)d_in[16];
  const int*   Ij   = (const int*)d_in[17];
  const int*   mol  = (const int*)d_in[18];
  const int N = in_sizes[15];
  const int E = in_sizes[16];
  const int M = out_size - N*3;
  const size_t NFE = (size_t)N*FD;
  float* outF = (float*)d_out;
  float* outE = outF + (size_t)N*3;
  float* ws = (float*)d_ws;
  if(ws_size < (11*NFE + 3*(size_t)E + 16)*4) return;

  float* X0  = ws;
  float* SV0 = ws + 4*NFE;
  float* H   = ws + 7*NFE;
  float* AGG = ws + 8*NFE;
  float* XB  = ws + 9*NFE;
  float* HB  = ws + 10*NFE;
  float* De  = ws + 11*NFE;
  float* DBe = De + E;
  int*   EA  = (int*)(DBe + E);
  int*   cnt = EA + E;
  float* G    = AGG;
  u32*  maxnU = (u32*)H;

  const int gN   = (int)((NFE + 255)/256);
  const int gE   = (E + 255)/256;
  const int gTF  = (E + TF-1)/TF;
  const int gTB  = (E + TB-1)/TB;
  const int gRow = (N + 63)/64;

  k_embed<<<gN,256,0,stream>>>(emb, Z, X0, (int)NFE);
  k_edge_geom<<<gE,256,0,stream>>>(pos, Ii, Ij, De, DBe, E);
  k_zero<<<1,256,0,stream>>>((float*)cnt, 1);
  k_compact<<<gE,256,0,stream>>>(De, EA, cnt, E);
  for(int l=0;l<3;l++){
    float* Xl  = X0 + (size_t)l*NFE;
    float* Xn  = X0 + (size_t)(l+1)*NFE;
    float* SVl = SV0 + (size_t)l*NFE;
    k_gemm32<<<gRow,256,0,stream>>>(Xl, in2f + l*16384, nullptr, nullptr, nullptr, H, nullptr, 0, 0, N);
    k_zero<<<gN,256,0,stream>>>(AGG, (int)NFE);
    k_edge_fwd4<<<gTF,256,0,stream>>>(H, Ii, Ij, De, EA, cnt, fW1 + l*2560, fb1 + l*128, fW2 + l*16384, fb2 + l*128, AGG);
    k_gemm32<<<gRow,256,0,stream>>>(AGG, oW1 + l*16384, ob1 + l*128, nullptr, nullptr, H, SVl, 0, 1, N);
    k_gemm32<<<gRow,256,0,stream>>>(H, oW2 + l*16384, ob2 + l*128, Xl, nullptr, Xn, nullptr, 0, 0, N);
  }
  k_zero<<<(M+255)/256,256,0,stream>>>(outE, M);
  k_head<<<gRow,256,0,stream>>>(X0 + 3*NFE, aW1, ab1, aW2, ab2, mol, outE, XB, N);
  for(int l=2;l>=0;l--){
    float* Xl  = X0 + (size_t)l*NFE;
    float* SVl = SV0 + (size_t)l*NFE;
    k_gemm32<<<gRow,256,0,stream>>>(XB, oW2 + l*16384, nullptr, nullptr, SVl, AGG, nullptr, 1, 0, N);
    k_gemm32<<<gRow,256,0,stream>>>(AGG, oW1 + l*16384, nullptr, nullptr, nullptr, AGG, nullptr, 1, 0, N);
    k_gemm32<<<gRow,256,0,stream>>>(Xl, in2f + l*16384, nullptr, nullptr, nullptr, H, nullptr, 0, 0, N);
    k_zero<<<gN,256,0,stream>>>(HB, (int)NFE);
    k_edge_bwd4<<<gTB,256,0,stream>>>(H, AGG, Ii, Ij, De, EA, cnt, fW1 + l*2560, fb1 + l*128, fW2 + l*16384, fb2 + l*128, DBe, HB);
    k_gemm32<<<gRow,256,0,stream>>>(HB, in2f + l*16384, nullptr, XB, nullptr, XB, nullptr, 1, 0, N);
  }
  k_zero<<<(N*3+255)/256,256,0,stream>>>(G, N*3);
  k_zero<<<(M+255)/256,256,0,stream>>>((float*)maxnU, M);
  k_grad<<<gE,256,0,stream>>>(pos, Ii, Ij, De, DBe, EA, cnt, G);
  k_norm<<<(N+255)/256,256,0,stream>>>(G, mol, maxnU, N);
  k_apply<<<(N+255)/256,256,0,stream>>>(G, mol, maxnU, outF, N);
}

// Round 12
// 3820.907 us; speedup vs baseline: 5.5160x; 1.3190x over previous
//
#include <hip/hip_runtime.h>
#include <cstddef>

// SchNet fwd energy + force bwd, MI355X. Round 12: single row-major W2 LDS
// layout (kills 16-way transposed-staging conflicts), sigma-trick (drops sSt),
// TB=32. MFMA tile GEMMs, coalesced scatter, cutoff compaction retained.

#define FD     128
#define NRBF   20
#define CUTF   5.0f
#define PI_F   3.14159265358979f
#define TF     32
#define TB     32
#define PW     136    // u16 pitch

typedef unsigned short u16;
typedef unsigned int   u32;
typedef __attribute__((ext_vector_type(8))) short bf16x8;
typedef __attribute__((ext_vector_type(4))) float f32x4;

__device__ __forceinline__ float u16f(u16 x){ union{u32 i; float f;} v; v.i=((u32)x)<<16; return v.f; }
__device__ __forceinline__ u16 f16r(float f){ union{float f; u32 i;} v; v.f=f; u32 r=v.i+0x7fffu+((v.i>>16)&1u); return (u16)(r>>16); }
__device__ __forceinline__ u32 pk2(float a,float b){ return (u32)f16r(a) | ((u32)f16r(b)<<16); }
__device__ __forceinline__ float sspf(float x){ return fmaxf(x,0.f)+log1pf(expf(-fabsf(x)))-0.6931471805599453f; }
__device__ __forceinline__ float sigf(float x){ return 1.f/(1.f+expf(-x)); }
__device__ __forceinline__ float fcutf(float d){ return (d < CUTF) ? 0.5f*(cosf(PI_F*d/CUTF)+1.f) : 0.f; }

__global__ __launch_bounds__(256) void k_zero(float* __restrict__ p, int n){
  int i = blockIdx.x*256 + threadIdx.x;
  if(i < n) p[i] = 0.f;
}

__global__ __launch_bounds__(256) void k_embed(const float* __restrict__ emb, const int* __restrict__ Z,
                                               float* __restrict__ X0, int n){
  int idx = blockIdx.x*256 + threadIdx.x;
  if(idx >= n) return;
  int a = idx >> 7, f = idx & 127;
  X0[idx] = emb[Z[a]*FD + f];
}

__global__ __launch_bounds__(256) void k_edge_geom(const float* __restrict__ pos,
    const int* __restrict__ Ii, const int* __restrict__ Ij,
    float* __restrict__ De, float* __restrict__ DBe, int E){
  int e = blockIdx.x*256 + threadIdx.x;
  if(e >= E) return;
  int i = Ii[e], j = Ij[e];
  float dx = pos[j*3+0]-pos[i*3+0];
  float dy = pos[j*3+1]-pos[i*3+1];
  float dz = pos[j*3+2]-pos[i*3+2];
  De[e] = sqrtf(dx*dx+dy*dy+dz*dz + 1e-12f);
  DBe[e] = 0.f;
}

__global__ __launch_bounds__(256) void k_compact(const float* __restrict__ De,
    int* __restrict__ EA, int* __restrict__ cnt, int E){
  int e = blockIdx.x*256 + threadIdx.x;
  if(e >= E) return;
  if(De[e] < CUTF){
    int p = atomicAdd(cnt, 1);
    EA[p] = e;
  }
}

// dense GEMM (unchanged, verified)
__global__ __launch_bounds__(256) void k_gemm32(const float* __restrict__ A, const float* __restrict__ B,
    const float* __restrict__ bias, const float* __restrict__ res,
    const float* __restrict__ mul, float* __restrict__ out1, float* __restrict__ out2,
    int transB, int act, int Nr){
  __shared__ float As[64*132];
  const int tid = threadIdx.x;
  const int rb = blockIdx.x * 64;
  for(int q=0;q<8;q++){
    int e = q*256 + tid;
    int r = e >> 5, c = (e & 31) * 4;
    int rr = rb + r; if(rr >= Nr) rr = Nr-1;
    *(float4*)&As[r*132 + c] = *(const float4*)(A + (size_t)rr*FD + c);
  }
  __syncthreads();
  const int r0 = (tid >> 4) * 4;
  const int f0 = (tid & 15) * 8;
  float acc[4][8] = {};
  if(!transB){
    for(int k=0;k<128;k++){
      float a[4] = {As[(r0+0)*132+k], As[(r0+1)*132+k], As[(r0+2)*132+k], As[(r0+3)*132+k]};
      float4 b0 = *(const float4*)(B + k*FD + f0);
      float4 b1 = *(const float4*)(B + k*FD + f0 + 4);
      float b[8] = {b0.x,b0.y,b0.z,b0.w,b1.x,b1.y,b1.z,b1.w};
      #pragma unroll
      for(int i=0;i<4;i++)
        #pragma unroll
        for(int j=0;j<8;j++) acc[i][j] += a[i]*b[j];
    }
  } else {
    for(int k=0;k<128;k++){
      float a[4] = {As[(r0+0)*132+k], As[(r0+1)*132+k], As[(r0+2)*132+k], As[(r0+3)*132+k]};
      float b[8];
      #pragma unroll
      for(int j=0;j<8;j++) b[j] = B[(size_t)(f0+j)*FD + k];
      #pragma unroll
      for(int i=0;i<4;i++)
        #pragma unroll
        for(int j=0;j<8;j++) acc[i][j] += a[i]*b[j];
    }
  }
  float bv[8];
  #pragma unroll
  for(int j=0;j<8;j++) bv[j] = bias ? bias[f0+j] : 0.f;
  #pragma unroll
  for(int rr=0;rr<4;rr++){
    int row = rb + r0 + rr;
    if(row >= Nr) break;
    size_t base = (size_t)row*FD + f0;
    float y[8];
    #pragma unroll
    for(int j=0;j<8;j++) y[j] = acc[rr][j] + bv[j];
    if(res){
      float4 r1 = *(const float4*)(res+base);
      float4 r2 = *(const float4*)(res+base+4);
      y[0]+=r1.x; y[1]+=r1.y; y[2]+=r1.z; y[3]+=r1.w;
      y[4]+=r2.x; y[5]+=r2.y; y[6]+=r2.z; y[7]+=r2.w;
    }
    if(mul){
      float4 m1 = *(const float4*)(mul+base);
      float4 m2 = *(const float4*)(mul+base+4);
      y[0]*=m1.x; y[1]*=m1.y; y[2]*=m1.z; y[3]*=m1.w;
      y[4]*=m2.x; y[5]*=m2.y; y[6]*=m2.z; y[7]*=m2.w;
    }
    if(act){
      *(float4*)(out1+base)   = make_float4(sspf(y[0]),sspf(y[1]),sspf(y[2]),sspf(y[3]));
      *(float4*)(out1+base+4) = make_float4(sspf(y[4]),sspf(y[5]),sspf(y[6]),sspf(y[7]));
      *(float4*)(out2+base)   = make_float4(sigf(y[0]),sigf(y[1]),sigf(y[2]),sigf(y[3]));
      *(float4*)(out2+base+4) = make_float4(sigf(y[4]),sigf(y[5]),sigf(y[6]),sigf(y[7]));
    } else {
      *(float4*)(out1+base)   = make_float4(y[0],y[1],y[2],y[3]);
      *(float4*)(out1+base+4) = make_float4(y[4],y[5],y[6],y[7]);
    }
  }
}

// ---- Edge forward v5: TF=32 edges/block, single row-major W2 ----
__global__ __launch_bounds__(256) void k_edge_fwd5(
    const float* __restrict__ h,
    const int* __restrict__ Ii, const int* __restrict__ Ij,
    const float* __restrict__ De,
    const int* __restrict__ EA, const int* __restrict__ cnt,
    const float* __restrict__ W1, const float* __restrict__ b1,
    const float* __restrict__ W2, const float* __restrict__ b2,
    float* __restrict__ agg){
  __shared__ u16 sW2[128*PW];    // [c][f] row-major
  __shared__ u16 sW1[NRBF*128];
  __shared__ u16 sP [TF*PW];     // P [e][c]
  __shared__ u16 sWf[TF*PW];     // Wf [e][f]
  __shared__ float srbf[TF*NRBF];
  __shared__ int sI[TF], sJ[TF];
  __shared__ float sFc[TF], sDd[TF];
  const int tid = threadIdx.x;
  const int C = *cnt;
  const int base = blockIdx.x*TF;
  if(base >= C) return;
  for(int q=0;q<16;q++){
    int idx = q*256 + tid;
    int c = idx >> 5, f4 = (idx & 31)*4;
    float4 v = *(const float4*)(W2 + c*FD + f4);
    *(u32*)&sW2[c*PW + f4]     = pk2(v.x, v.y);
    *(u32*)&sW2[c*PW + f4 + 2] = pk2(v.z, v.w);
  }
  for(int q=0;q<10;q++){ int idx=q*256+tid; sW1[idx]=f16r(W1[idx]); }
  if(tid < TF){
    int idx = base + tid;
    if(idx < C){
      int e = EA[idx];
      sI[tid]=Ii[e]; sJ[tid]=Ij[e];
      float d = De[e];
      sFc[tid]=fcutf(d); sDd[tid]=d;
    } else { sI[tid]=0; sJ[tid]=0; sFc[tid]=0.f; sDd[tid]=1.f; }
  }
  __syncthreads();
  const float step = CUTF/19.0f;
  const float coef = -0.5f/(step*step);
  for(int idx=tid; idx<TF*NRBF; idx+=256){
    int t = idx/NRBF, k = idx%NRBF;
    float x = sDd[t] - step*(float)k;
    srbf[idx] = expf(coef*x*x);
  }
  __syncthreads();
  { // P[t][c], 8 threads/edge
    const int t = tid >> 3, oq = tid & 7;
    #pragma unroll
    for(int kk=0; kk<16; kk++){
      int c = oq + 8*kk;
      float tv = b1[c];
      #pragma unroll
      for(int k=0;k<NRBF;k++) tv += srbf[t*NRBF+k]*u16f(sW1[k*128 + c]);
      sP[t*PW + c] = f16r(sspf(tv));
    }
  }
  __syncthreads();
  const int w = tid >> 6, lane = tid & 63;
  const int quad = lane >> 4, l16 = lane & 15;
  { // MFMA: Wf = P@W2 + b2; wave w -> n-tiles {2w,2w+1}, m-tiles 0..1
    f32x4 acc[2][2];
    #pragma unroll
    for(int m=0;m<2;m++){ acc[m][0]=(f32x4){0,0,0,0}; acc[m][1]=(f32x4){0,0,0,0}; }
    #pragma unroll
    for(int ks=0;ks<4;ks++){
      bf16x8 a[2], b[2];
      #pragma unroll
      for(int m=0;m<2;m++)
        a[m] = *(const bf16x8*)&sP[(m*16+l16)*PW + ks*32 + quad*8];
      #pragma unroll
      for(int p=0;p<2;p++){
        const int f = (2*w+p)*16 + l16;
        #pragma unroll
        for(int j=0;j<8;j++) b[p][j] = (short)sW2[(ks*32 + quad*8 + j)*PW + f];
      }
      #pragma unroll
      for(int m=0;m<2;m++)
        #pragma unroll
        for(int p=0;p<2;p++)
          acc[m][p] = __builtin_amdgcn_mfma_f32_16x16x32_bf16(a[m], b[p], acc[m][p], 0,0,0);
    }
    #pragma unroll
    for(int m=0;m<2;m++)
      #pragma unroll
      for(int p=0;p<2;p++){
        const int f = (2*w+p)*16 + l16;
        float bb = b2[f];
        #pragma unroll
        for(int r=0;r<4;r++)
          sWf[(m*16+quad*4+r)*PW + f] = f16r(acc[m][p][r] + bb);
      }
  }
  __syncthreads();
  { // coalesced scatter
    for(int s=0;s<8;s++){
      int tt = w*8 + s;
      if(base + tt >= C) continue;
      int i = sI[tt], j = sJ[tt];
      float fc = sFc[tt];
      float h0 = h[(size_t)j*FD + lane];
      float h1 = h[(size_t)j*FD + lane + 64];
      float w0 = u16f(sWf[tt*PW + lane]);
      float w1 = u16f(sWf[tt*PW + lane + 64]);
      atomicAdd(&agg[(size_t)i*FD + lane],      h0*w0*fc);
      atomicAdd(&agg[(size_t)i*FD + lane + 64], h1*w1*fc);
    }
  }
}

// ---- Edge backward v5: TB=32 edges/block, single W2 layout, sigma-trick ----
__global__ __launch_bounds__(256) void k_edge_bwd5(
    const float* __restrict__ h, const float* __restrict__ AB,
    const int* __restrict__ Ii, const int* __restrict__ Ij,
    const float* __restrict__ De,
    const int* __restrict__ EA, const int* __restrict__ cnt,
    const float* __restrict__ W1, const float* __restrict__ b1,
    const float* __restrict__ W2, const float* __restrict__ b2,
    float* __restrict__ DBe, float* __restrict__ HB){
  __shared__ u16 sW2[128*PW];    // [c][f] row-major (only layout)
  __shared__ u16 sW1[NRBF*128];
  __shared__ u16 sP [TB*PW];     // P [e][c] (kept whole kernel)
  __shared__ u16 sWf[TB*PW];     // Wf -> Wbar -> tbar
  __shared__ float srbf[TB*NRBF];
  __shared__ int sI[TB], sJ[TB], sE[TB];
  __shared__ float sFc[TB], sDd[TB], sfb[TB];
  const int tid = threadIdx.x;
  const int C = *cnt;
  const int base = blockIdx.x*TB;
  if(base >= C) return;
  for(int q=0;q<16;q++){
    int idx = q*256 + tid;
    int c = idx >> 5, f4 = (idx & 31)*4;
    float4 v = *(const float4*)(W2 + c*FD + f4);
    *(u32*)&sW2[c*PW + f4]     = pk2(v.x, v.y);
    *(u32*)&sW2[c*PW + f4 + 2] = pk2(v.z, v.w);
  }
  for(int q=0;q<10;q++){ int idx=q*256+tid; sW1[idx]=f16r(W1[idx]); }
  if(tid < TB){
    int idx = base + tid;
    if(idx < C){
      int e = EA[idx];
      sE[tid]=e; sI[tid]=Ii[e]; sJ[tid]=Ij[e];
      float d = De[e];
      sFc[tid]=fcutf(d); sDd[tid]=d;
    } else { sE[tid]=0; sI[tid]=0; sJ[tid]=0; sFc[tid]=0.f; sDd[tid]=1.f; }
  }
  __syncthreads();
  const float step = CUTF/19.0f;
  const float coef = -0.5f/(step*step);
  for(int idx=tid; idx<TB*NRBF; idx+=256){
    int t = idx/NRBF, k = idx%NRBF;
    float x = sDd[t] - step*(float)k;
    srbf[idx] = expf(coef*x*x);
  }
  __syncthreads();
  { // P phase: 8 threads/edge (no sigf; sigma recovered later)
    const int t = tid >> 3, oq = tid & 7;
    #pragma unroll
    for(int kk=0; kk<16; kk++){
      int c = oq + 8*kk;
      float tv = b1[c];
      #pragma unroll
      for(int k=0;k<NRBF;k++) tv += srbf[t*NRBF+k]*u16f(sW1[k*128 + c]);
      sP[t*PW + c] = f16r(sspf(tv));
    }
  }
  __syncthreads();
  const int w = tid >> 6, lane = tid & 63;
  const int quad = lane >> 4, l16 = lane & 15;
  { // GEMM1 MFMA: Wf = P@W2 + b2 (B via column u16 loads)
    f32x4 acc[2][2];
    #pragma unroll
    for(int m=0;m<2;m++){ acc[m][0]=(f32x4){0,0,0,0}; acc[m][1]=(f32x4){0,0,0,0}; }
    #pragma unroll
    for(int ks=0;ks<4;ks++){
      bf16x8 a[2], b[2];
      #pragma unroll
      for(int m=0;m<2;m++)
        a[m] = *(const bf16x8*)&sP[(m*16+l16)*PW + ks*32 + quad*8];
      #pragma unroll
      for(int p=0;p<2;p++){
        const int f = (2*w+p)*16 + l16;
        #pragma unroll
        for(int j=0;j<8;j++) b[p][j] = (short)sW2[(ks*32 + quad*8 + j)*PW + f];
      }
      #pragma unroll
      for(int m=0;m<2;m++)
        #pragma unroll
        for(int p=0;p<2;p++)
          acc[m][p] = __builtin_amdgcn_mfma_f32_16x16x32_bf16(a[m], b[p], acc[m][p], 0,0,0);
    }
    #pragma unroll
    for(int m=0;m<2;m++)
      #pragma unroll
      for(int p=0;p<2;p++){
        const int f = (2*w+p)*16 + l16;
        float bb = b2[f];
        #pragma unroll
        for(int r=0;r<4;r++)
          sWf[(m*16+quad*4+r)*PW + f] = f16r(acc[m][p][r] + bb);
      }
  }
  __syncthreads();
  { // scatter + Wbar (in-place per-element into sWf) + fbar
    for(int s=0;s<8;s++){
      int tt = w*8 + s;
      if(base + tt >= C) continue;
      int i = sI[tt], j = sJ[tt];
      float fc = sFc[tt];
      float a0 = AB[(size_t)i*FD + lane];
      float a1 = AB[(size_t)i*FD + lane + 64];
      float h0 = h [(size_t)j*FD + lane];
      float h1 = h [(size_t)j*FD + lane + 64];
      float w0 = u16f(sWf[tt*PW + lane]);
      float w1 = u16f(sWf[tt*PW + lane + 64]);
      atomicAdd(&HB[(size_t)j*FD + lane],      a0*w0*fc);
      atomicAdd(&HB[(size_t)j*FD + lane + 64], a1*w1*fc);
      float g0 = a0*h0, g1 = a1*h1;
      sWf[tt*PW + lane]      = f16r(g0*fc);
      sWf[tt*PW + lane + 64] = f16r(g1*fc);
      float pf = g0*w0 + g1*w1;
      #pragma unroll
      for(int d2=1; d2<64; d2<<=1) pf += __shfl_xor(pf, d2);
      if(lane == 0) sfb[tt] = pf;
    }
  }
  __syncthreads();
  float tb[2][2][4];
  { // GEMM2 MFMA: Pbar = Wbar@W2^T (B = sW2 rows, b128); sigma-trick epilogue into regs
    f32x4 acc[2][2];
    #pragma unroll
    for(int m=0;m<2;m++){ acc[m][0]=(f32x4){0,0,0,0}; acc[m][1]=(f32x4){0,0,0,0}; }
    #pragma unroll
    for(int ks=0;ks<4;ks++){
      bf16x8 a[2], b[2];
      #pragma unroll
      for(int m=0;m<2;m++)
        a[m] = *(const bf16x8*)&sWf[(m*16+l16)*PW + ks*32 + quad*8];
      #pragma unroll
      for(int p=0;p<2;p++)
        b[p] = *(const bf16x8*)&sW2[((2*w+p)*16+l16)*PW + ks*32 + quad*8];
      #pragma unroll
      for(int m=0;m<2;m++)
        #pragma unroll
        for(int p=0;p<2;p++)
          acc[m][p] = __builtin_amdgcn_mfma_f32_16x16x32_bf16(a[m], b[p], acc[m][p], 0,0,0);
    }
    #pragma unroll
    for(int m=0;m<2;m++)
      #pragma unroll
      for(int p=0;p<2;p++){
        const int c = (2*w+p)*16 + l16;
        #pragma unroll
        for(int r=0;r<4;r++){
          float Pv = u16f(sP[(m*16+quad*4+r)*PW + c]);
          float sig = 1.0f - 0.5f*expf(-Pv);
          tb[m][p][r] = acc[m][p][r] * sig;
        }
      }
  }
  __syncthreads();   // all Wbar fragment reads complete
  { // write tbar into sWf
    #pragma unroll
    for(int m=0;m<2;m++)
      #pragma unroll
      for(int p=0;p<2;p++){
        const int c = (2*w+p)*16 + l16;
        #pragma unroll
        for(int r=0;r<4;r++)
          sWf[(m*16+quad*4+r)*PW + c] = f16r(tb[m][p][r]);
      }
  }
  __syncthreads();
  { // GEMM3 (VALU): rbar = tbar@W1^T, 8 threads/edge; dbar
    const int t = tid >> 3, oq = tid & 7;
    const bool ok = (base + t < C);
    float a20[NRBF] = {};
    #pragma unroll
    for(int kk=0;kk<16;kk++){
      int c = oq + 8*kk;
      float tv = u16f(sWf[t*PW + c]);
      #pragma unroll
      for(int k=0;k<NRBF;k++) a20[k] += tv * u16f(sW1[k*128 + c]);
    }
    #pragma unroll
    for(int k=0;k<NRBF;k++){
      a20[k] += __shfl_xor(a20[k],1);
      a20[k] += __shfl_xor(a20[k],2);
      a20[k] += __shfl_xor(a20[k],4);
    }
    if(oq == 0 && ok){
      const float d = sDd[t];
      float drb = 0.f;
      #pragma unroll
      for(int k=0;k<NRBF;k++){
        float x = d - step*(float)k;
        drb += a20[k] * srbf[t*NRBF+k] * 2.f*coef*x;
      }
      float dfc = (d < CUTF) ? (-0.5f*(PI_F/CUTF)*sinf(PI_F*d/CUTF)) : 0.f;
      DBe[sE[t]] += drb + sfb[t]*dfc;
    }
  }
}

// fused atomwise head + head-backward (unchanged, verified)
__global__ __launch_bounds__(256) void k_head(const float* __restrict__ X3,
    const float* __restrict__ aW1, const float* __restrict__ ab1,
    const float* __restrict__ aW2, const float* __restrict__ ab2,
    const int* __restrict__ mol, float* __restrict__ Emol, float* __restrict__ XB, int N){
  __shared__ float sx[64*129];
  __shared__ float sg[64*65];
  const int tid = threadIdx.x;
  const int base = blockIdx.x*64;
  for(int q=0;q<8;q++){
    int ee = q*256 + tid;
    int r = ee >> 5, c = (ee & 31)*4;
    int row = base + r; if(row >= N) row = N-1;
    float4 v = *(const float4*)(X3 + (size_t)row*FD + c);
    sx[r*129 + c+0] = v.x; sx[r*129 + c+1] = v.y;
    sx[r*129 + c+2] = v.z; sx[r*129 + c+3] = v.w;
  }
  __syncthreads();
  {
    const int a = tid >> 2, q = tid & 3;
    float pe = 0.f;
    for(int cc=0; cc<16; cc++){
      int c = q*16 + cc;
      float u = ab1[c];
      for(int f=0; f<128; f++) u += sx[a*129 + f]*aW1[f*64 + c];
      pe += sspf(u)*aW2[c];
      sg[a*65 + c] = sigf(u)*aW2[c];
    }
    pe += __shfl_xor(pe, 1);
    pe += __shfl_xor(pe, 2);
    if(q == 0 && base + a < N) atomicAdd(&Emol[mol[base + a]], pe + ab2[0]);
  }
  __syncthreads();
  {
    const int f = tid & 127, g2 = tid >> 7;
    float acc[32];
    #pragma unroll
    for(int q=0;q<32;q++) acc[q]=0.f;
    for(int c=0;c<64;c++){
      float w = aW1[f*64 + c];
      #pragma unroll
      for(int q=0;q<32;q++) acc[q] += sg[(g2*32+q)*65 + c]*w;
    }
    #pragma unroll
    for(int q=0;q<32;q++){
      int row = base + g2*32 + q;
      if(row < N) XB[(size_t)row*FD + f] = acc[q];
    }
  }
}

__global__ __launch_bounds__(256) void k_grad(const float* __restrict__ pos,
    const int* __restrict__ Ii, const int* __restrict__ Ij,
    const float* __restrict__ De, const float* __restrict__ DBe,
    const int* __restrict__ EA, const int* __restrict__ cnt,
    float* __restrict__ G){
  int idx = blockIdx.x*256 + threadIdx.x;
  if(idx >= *cnt) return;
  int e = EA[idx];
  float s = DBe[e] / De[e];
  int i = Ii[e], j = Ij[e];
  float dx = s*(pos[i*3+0]-pos[j*3+0]);
  float dy = s*(pos[i*3+1]-pos[j*3+1]);
  float dz = s*(pos[i*3+2]-pos[j*3+2]);
  atomicAdd(&G[i*3+0], dx); atomicAdd(&G[i*3+1], dy); atomicAdd(&G[i*3+2], dz);
  atomicAdd(&G[j*3+0], -dx); atomicAdd(&G[j*3+1], -dy); atomicAdd(&G[j*3+2], -dz);
}

__global__ __launch_bounds__(256) void k_norm(const float* __restrict__ G,
    const int* __restrict__ mol, u32* __restrict__ maxnU, int N){
  int n = blockIdx.x*256 + threadIdx.x;
  if(n >= N) return;
  float ax = G[n*3], ay = G[n*3+1], az = G[n*3+2];
  float nrm = sqrtf(ax*ax+ay*ay+az*az);
  atomicMax(&maxnU[mol[n]], __float_as_uint(nrm));
}

__global__ __launch_bounds__(256) void k_apply(const float* __restrict__ G,
    const int* __restrict__ mol, const u32* __restrict__ maxnU,
    float* __restrict__ outA, int N){
  int n = blockIdx.x*256 + threadIdx.x;
  if(n >= N) return;
  float mx = __uint_as_float(maxnU[mol[n]]);
  float coefc = fminf(1.0f/fmaxf(mx, 1e-8f), 1.0f);
  outA[n*3+0] = -G[n*3+0]*coefc;
  outA[n*3+1] = -G[n*3+1]*coefc;
  outA[n*3+2] = -G[n*3+2]*coefc;
}

extern "C" void kernel_launch(void* const* d_in, const int* in_sizes, int n_in,
                              void* d_out, int out_size, void* d_ws, size_t ws_size,
                              hipStream_t stream) {
  (void)n_in;
  const float* pos  = (const float*)d_in[0];
  const float* emb  = (const float*)d_in[1];
  const float* in2f = (const float*)d_in[2];
  const float* fW1  = (const float*)d_in[3];
  const float* fb1  = (const float*)d_in[4];
  const float* fW2  = (const float*)d_in[5];
  const float* fb2  = (const float*)d_in[6];
  const float* oW1  = (const float*)d_in[7];
  const float* ob1  = (const float*)d_in[8];
  const float* oW2  = (const float*)d_in[9];
  const float* ob2  = (const float*)d_in[10];
  const float* aW1  = (const float*)d_in[11];
  const float* ab1  = (const float*)d_in[12];
  const float* aW2  = (const float*)d_in[13];
  const float* ab2  = (const float*)d_in[14];
  const int*   Z    = (const int*)d_in[15];
  const int*   Ii   = (const int*)d_in[16];
  const int*   Ij   = (const int*)d_in[17];
  const int*   mol  = (const int*)d_in[18];
  const int N = in_sizes[15];
  const int E = in_sizes[16];
  const int M = out_size - N*3;
  const size_t NFE = (size_t)N*FD;
  float* outF = (float*)d_out;
  float* outE = outF + (size_t)N*3;
  float* ws = (float*)d_ws;
  if(ws_size < (11*NFE + 3*(size_t)E + 16)*4) return;

  float* X0  = ws;
  float* SV0 = ws + 4*NFE;
  float* H   = ws + 7*NFE;
  float* AGG = ws + 8*NFE;
  float* XB  = ws + 9*NFE;
  float* HB  = ws + 10*NFE;
  float* De  = ws + 11*NFE;
  float* DBe = De + E;
  int*   EA  = (int*)(DBe + E);
  int*   cnt = EA + E;
  float* G    = AGG;
  u32*  maxnU = (u32*)H;

  const int gN   = (int)((NFE + 255)/256);
  const int gE   = (E + 255)/256;
  const int gTF  = (E + TF-1)/TF;
  const int gTB  = (E + TB-1)/TB;
  const int gRow = (N + 63)/64;

  k_embed<<<gN,256,0,stream>>>(emb, Z, X0, (int)NFE);
  k_edge_geom<<<gE,256,0,stream>>>(pos, Ii, Ij, De, DBe, E);
  k_zero<<<1,256,0,stream>>>((float*)cnt, 1);
  k_compact<<<gE,256,0,stream>>>(De, EA, cnt, E);
  for(int l=0;l<3;l++){
    float* Xl  = X0 + (size_t)l*NFE;
    float* Xn  = X0 + (size_t)(l+1)*NFE;
    float* SVl = SV0 + (size_t)l*NFE;
    k_gemm32<<<gRow,256,0,stream>>>(Xl, in2f + l*16384, nullptr, nullptr, nullptr, H, nullptr, 0, 0, N);
    k_zero<<<gN,256,0,stream>>>(AGG, (int)NFE);
    k_edge_fwd5<<<gTF,256,0,stream>>>(H, Ii, Ij, De, EA, cnt, fW1 + l*2560, fb1 + l*128, fW2 + l*16384, fb2 + l*128, AGG);
    k_gemm32<<<gRow,256,0,stream>>>(AGG, oW1 + l*16384, ob1 + l*128, nullptr, nullptr, H, SVl, 0, 1, N);
    k_gemm32<<<gRow,256,0,stream>>>(H, oW2 + l*16384, ob2 + l*128, Xl, nullptr, Xn, nullptr, 0, 0, N);
  }
  k_zero<<<(M+255)/256,256,0,stream>>>(outE, M);
  k_head<<<gRow,256,0,stream>>>(X0 + 3*NFE, aW1, ab1, aW2, ab2, mol, outE, XB, N);
  for(int l=2;l>=0;l--){
    float* Xl  = X0 + (size_t)l*NFE;
    float* SVl = SV0 + (size_t)l*NFE;
    k_gemm32<<<gRow,256,0,stream>>>(XB, oW2 + l*16384, nullptr, nullptr, SVl, AGG, nullptr, 1, 0, N);
    k_gemm32<<<gRow,256,0,stream>>>(AGG, oW1 + l*16384, nullptr, nullptr, nullptr, AGG, nullptr, 1, 0, N);
    k_gemm32<<<gRow,256,0,stream>>>(Xl, in2f + l*16384, nullptr, nullptr, nullptr, H, nullptr, 0, 0, N);
    k_zero<<<gN,256,0,stream>>>(HB, (int)NFE);
    k_edge_bwd5<<<gTB,256,0,stream>>>(H, AGG, Ii, Ij, De, EA, cnt, fW1 + l*2560, fb1 + l*128, fW2 + l*16384, fb2 + l*128, DBe, HB);
    k_gemm32<<<gRow,256,0,stream>>>(HB, in2f + l*16384, nullptr, XB, nullptr, XB, nullptr, 1, 0, N);
  }
  k_zero<<<(N*3+255)/256,256,0,stream>>>(G, N*3);
  k_zero<<<(M+255)/256,256,0,stream>>>((float*)maxnU, M);
  k_grad<<<gE,256,0,stream>>>(pos, Ii, Ij, De, DBe, EA, cnt, G);
  k_norm<<<(N+255)/256,256,0,stream>>>(G, mol, maxnU, N);
  k_apply<<<(N+255)/256,256,0,stream>>>(G, mol, maxnU, outF, N);
}